// Round 1
// baseline (478.956 us; speedup 1.0000x reference)
//
#include <hip/hip_runtime.h>
#include <cstdint>
#include <cstddef>

#define BATCH 8
#define NPTS  8192
#define MPTS  2048
#define C1    128
#define C2    256
#define K0    384   // C1 + C2
#define O0    256
#define O1    128
#define NROWS (BATCH * NPTS)  // 65536

// ---------------------------------------------------------------------------
// Kernel 1: brute-force 3-NN + inverse-distance weights.
// One block = 256 query points of one batch; xyz2 of that batch cached in LDS
// as float4 (x,y,z,|p|^2).  Distance arithmetic replicates the reference
// ( -2*dot + |x|^2 + |y|^2, left-assoc, no FMA contraction ) so the top-3
// selection matches the numpy reference at near-ties.
// ---------------------------------------------------------------------------
__global__ __launch_bounds__(256) void k_knn(const float* __restrict__ xyz1,
                                             const float* __restrict__ xyz2,
                                             int* __restrict__ idxo,
                                             float* __restrict__ wo) {
    __shared__ float4 s2[MPTS];
    const int b = blockIdx.x >> 5;      // 32 chunks per batch
    const int chunk = blockIdx.x & 31;

    for (int p = threadIdx.x; p < MPTS; p += 256) {
        const size_t src = ((size_t)b * MPTS + p) * 3;
        float px = xyz2[src + 0], py = xyz2[src + 1], pz = xyz2[src + 2];
        float sy = __fadd_rn(__fadd_rn(__fmul_rn(px, px), __fmul_rn(py, py)),
                             __fmul_rn(pz, pz));
        s2[p] = make_float4(px, py, pz, sy);
    }
    __syncthreads();

    const int n = chunk * 256 + threadIdx.x;
    const size_t q = ((size_t)b * NPTS + n) * 3;
    const float qx = xyz1[q + 0], qy = xyz1[q + 1], qz = xyz1[q + 2];
    const float sx = __fadd_rn(__fadd_rn(__fmul_rn(qx, qx), __fmul_rn(qy, qy)),
                               __fmul_rn(qz, qz));

    float d0 = 3.0e38f, d1 = 3.0e38f, d2 = 3.0e38f;
    int i0 = 0, i1 = 0, i2 = 0;
#pragma unroll 8
    for (int m = 0; m < MPTS; ++m) {
        float4 pp = s2[m];
        float dot = __fadd_rn(__fadd_rn(__fmul_rn(qx, pp.x), __fmul_rn(qy, pp.y)),
                              __fmul_rn(qz, pp.z));
        float d = __fadd_rn(__fadd_rn(__fmul_rn(-2.0f, dot), sx), pp.w);
        if (d < d2) {
            if (d < d1) {
                d2 = d1; i2 = i1;
                if (d < d0) { d1 = d0; i1 = i0; d0 = d; i0 = m; }
                else        { d1 = d;  i1 = m; }
            } else { d2 = d; i2 = m; }
        }
    }

    const float r0 = 1.0f / __fadd_rn(d0, 1e-8f);
    const float r1 = 1.0f / __fadd_rn(d1, 1e-8f);
    const float r2 = 1.0f / __fadd_rn(d2, 1e-8f);
    const float norm = __fadd_rn(__fadd_rn(r0, r1), r2);

    const size_t row = (size_t)b * NPTS + n;
    idxo[row * 3 + 0] = i0; idxo[row * 3 + 1] = i1; idxo[row * 3 + 2] = i2;
    wo[row * 3 + 0] = r0 / norm;
    wo[row * 3 + 1] = r1 / norm;
    wo[row * 3 + 2] = r2 / norm;
}

// ---------------------------------------------------------------------------
// Kernel 2: gather + interpolate + concat -> x[65536][384]
// block = 384 threads (one output column each), 8 rows per block.
// ---------------------------------------------------------------------------
__global__ __launch_bounds__(384) void k_interp(const float* __restrict__ p1,
                                                const float* __restrict__ p2,
                                                const int* __restrict__ idx,
                                                const float* __restrict__ w,
                                                float* __restrict__ x) {
    const int t = threadIdx.x;
    const int row0 = blockIdx.x * 8;
#pragma unroll
    for (int r = 0; r < 8; ++r) {
        const int row = row0 + r;
        const int b = row >> 13;  // / NPTS
        const int i0 = idx[row * 3 + 0];
        const int i1 = idx[row * 3 + 1];
        const int i2 = idx[row * 3 + 2];
        const float w0 = w[row * 3 + 0];
        const float w1 = w[row * 3 + 1];
        const float w2 = w[row * 3 + 2];
        float v;
        if (t < C1) {
            v = p1[(size_t)row * C1 + t];
        } else {
            const int cc = t - C1;
            const size_t base = (size_t)b * MPTS * C2;
            v = w0 * p2[base + (size_t)i0 * C2 + cc]
              + w1 * p2[base + (size_t)i1 * C2 + cc]
              + w2 * p2[base + (size_t)i2 * C2 + cc];
        }
        x[(size_t)row * K0 + t] = v;
    }
}

// ---------------------------------------------------------------------------
// Small transpose: W0[256][384] -> W0t[384][256], W1[128][256] -> W1t[256][128]
// ---------------------------------------------------------------------------
__global__ __launch_bounds__(256) void k_tr(const float* __restrict__ W0,
                                            const float* __restrict__ W1,
                                            float* __restrict__ W0t,
                                            float* __restrict__ W1t) {
    const int e = blockIdx.x * 256 + threadIdx.x;
    if (e < O0 * K0) {
        const int k = e >> 8, o = e & 255;
        W0t[e] = W0[o * K0 + k];
    }
    const int e2 = e - O0 * K0;
    if (e2 >= 0 && e2 < O1 * O0) {
        const int k = e2 >> 7, o = e2 & 127;
        W1t[e2] = W1[o * O0 + k];
    }
}

// ---------------------------------------------------------------------------
// GEMM0: y0[65536][256] = x[65536][384] @ W0t + b0   (pre-BN output)
// BM=64 BN=256 BK=16, 256 threads, 8x8 microtile (cols split tc*4 / tc*4+128).
// ---------------------------------------------------------------------------
__global__ __launch_bounds__(256) void k_gemm0(const float* __restrict__ x,
                                               const float* __restrict__ Wt,
                                               const float* __restrict__ bias,
                                               float* __restrict__ y) {
    __shared__ float As[16][68];   // [k][row], padded: 68*4B = 16B-aligned rows
    __shared__ float Bs[16][256];  // [k][col]
    const int t = threadIdx.x;
    const int r0 = blockIdx.x * 64;
    const int tr = t >> 5;        // 0..7  -> 8 rows
    const int tc = t & 31;        // 0..31 -> 4+4 cols
    const int lr = t >> 2;        // 0..63
    const int lk4 = (t & 3) << 2; // 0,4,8,12

    float acc[8][8];
#pragma unroll
    for (int i = 0; i < 8; ++i)
#pragma unroll
        for (int j = 0; j < 8; ++j) acc[i][j] = 0.0f;

    for (int kt = 0; kt < K0; kt += 16) {
        float4 av = *(const float4*)&x[(size_t)(r0 + lr) * K0 + kt + lk4];
        As[lk4 + 0][lr] = av.x;
        As[lk4 + 1][lr] = av.y;
        As[lk4 + 2][lr] = av.z;
        As[lk4 + 3][lr] = av.w;
        {
            const int kk = t >> 4;         // 0..15
            const int c4 = (t & 15) << 4;  // 0..240
            const float4* src = (const float4*)&Wt[(size_t)(kt + kk) * O0 + c4];
            float4* dst = (float4*)&Bs[kk][c4];
            dst[0] = src[0]; dst[1] = src[1]; dst[2] = src[2]; dst[3] = src[3];
        }
        __syncthreads();
#pragma unroll
        for (int kk = 0; kk < 16; ++kk) {
            float a[8], b[8];
            *(float4*)&a[0] = *(const float4*)&As[kk][tr * 8];
            *(float4*)&a[4] = *(const float4*)&As[kk][tr * 8 + 4];
            *(float4*)&b[0] = *(const float4*)&Bs[kk][tc * 4];
            *(float4*)&b[4] = *(const float4*)&Bs[kk][tc * 4 + 128];
#pragma unroll
            for (int i = 0; i < 8; ++i)
#pragma unroll
                for (int j = 0; j < 8; ++j)
                    acc[i][j] = fmaf(a[i], b[j], acc[i][j]);
        }
        __syncthreads();
    }

    const float4 b0v = *(const float4*)&bias[tc * 4];
    const float4 b1v = *(const float4*)&bias[tc * 4 + 128];
#pragma unroll
    for (int i = 0; i < 8; ++i) {
        const size_t row = (size_t)(r0 + tr * 8 + i);
        float4 o0 = make_float4(acc[i][0] + b0v.x, acc[i][1] + b0v.y,
                                acc[i][2] + b0v.z, acc[i][3] + b0v.w);
        float4 o1 = make_float4(acc[i][4] + b1v.x, acc[i][5] + b1v.y,
                                acc[i][6] + b1v.z, acc[i][7] + b1v.w);
        *(float4*)&y[row * O0 + tc * 4] = o0;
        *(float4*)&y[row * O0 + tc * 4 + 128] = o1;
    }
}

// ---------------------------------------------------------------------------
// Column stats (deterministic two-stage): per-block partial sum/sumsq.
// ---------------------------------------------------------------------------
__global__ __launch_bounds__(256) void k_stats0(const float* __restrict__ y,
                                                float* __restrict__ ps,
                                                float* __restrict__ pq) {
    const int t = threadIdx.x;
    const int r0 = blockIdx.x * 256;
    float s = 0.0f, q = 0.0f;
    for (int r = 0; r < 256; ++r) {
        float v = y[(size_t)(r0 + r) * O0 + t];
        s += v;
        q = fmaf(v, v, q);
    }
    ps[blockIdx.x * O0 + t] = s;
    pq[blockIdx.x * O0 + t] = q;
}

__global__ __launch_bounds__(256) void k_fin0(const float* __restrict__ ps,
                                              const float* __restrict__ pq,
                                              const float* __restrict__ gamma,
                                              const float* __restrict__ beta,
                                              float* __restrict__ sc,
                                              float* __restrict__ sh) {
    const int c = threadIdx.x;
    float s = 0.0f, q = 0.0f;
    for (int b = 0; b < 256; ++b) { s += ps[b * O0 + c]; q += pq[b * O0 + c]; }
    const float mean = s * (1.0f / NROWS);
    const float var = q * (1.0f / NROWS) - mean * mean;
    const float rs = rsqrtf(var + 1e-5f);
    const float scale = gamma[c] * rs;
    sc[c] = scale;
    sh[c] = beta[c] - mean * scale;
}

// ---------------------------------------------------------------------------
// GEMM1: out_pre[65536][128] = relu(BN0(y0)) @ W1t + b1  (BN0 fused on load)
// BM=64 BN=128 BK=16, 256 threads, 8x4 microtile.  Writes pre-BN y1 to d_out.
// ---------------------------------------------------------------------------
__global__ __launch_bounds__(256) void k_gemm1(const float* __restrict__ y0,
                                               const float* __restrict__ Wt,
                                               const float* __restrict__ bias,
                                               const float* __restrict__ sc,
                                               const float* __restrict__ sh,
                                               float* __restrict__ y1) {
    __shared__ float As[16][68];
    __shared__ float Bs[16][128];
    const int t = threadIdx.x;
    const int r0 = blockIdx.x * 64;
    const int tr = t >> 5;        // 0..7
    const int tc = t & 31;        // 0..31 -> cols tc*4..+3
    const int lr = t >> 2;
    const int lk4 = (t & 3) << 2;

    float acc[8][4];
#pragma unroll
    for (int i = 0; i < 8; ++i)
#pragma unroll
        for (int j = 0; j < 4; ++j) acc[i][j] = 0.0f;

    for (int kt = 0; kt < O0; kt += 16) {
        const int c = kt + lk4;
        float4 av = *(const float4*)&y0[(size_t)(r0 + lr) * O0 + c];
        av.x = fmaxf(fmaf(av.x, sc[c + 0], sh[c + 0]), 0.0f);
        av.y = fmaxf(fmaf(av.y, sc[c + 1], sh[c + 1]), 0.0f);
        av.z = fmaxf(fmaf(av.z, sc[c + 2], sh[c + 2]), 0.0f);
        av.w = fmaxf(fmaf(av.w, sc[c + 3], sh[c + 3]), 0.0f);
        As[lk4 + 0][lr] = av.x;
        As[lk4 + 1][lr] = av.y;
        As[lk4 + 2][lr] = av.z;
        As[lk4 + 3][lr] = av.w;
        {
            const int kk = t >> 4;        // 0..15
            const int c8 = (t & 15) << 3; // 0..120
            const float4* src = (const float4*)&Wt[(size_t)(kt + kk) * O1 + c8];
            float4* dst = (float4*)&Bs[kk][c8];
            dst[0] = src[0]; dst[1] = src[1];
        }
        __syncthreads();
#pragma unroll
        for (int kk = 0; kk < 16; ++kk) {
            float a[8], b[4];
            *(float4*)&a[0] = *(const float4*)&As[kk][tr * 8];
            *(float4*)&a[4] = *(const float4*)&As[kk][tr * 8 + 4];
            *(float4*)&b[0] = *(const float4*)&Bs[kk][tc * 4];
#pragma unroll
            for (int i = 0; i < 8; ++i)
#pragma unroll
                for (int j = 0; j < 4; ++j)
                    acc[i][j] = fmaf(a[i], b[j], acc[i][j]);
        }
        __syncthreads();
    }

    const float4 bv = *(const float4*)&bias[tc * 4];
#pragma unroll
    for (int i = 0; i < 8; ++i) {
        const size_t row = (size_t)(r0 + tr * 8 + i);
        float4 o = make_float4(acc[i][0] + bv.x, acc[i][1] + bv.y,
                               acc[i][2] + bv.z, acc[i][3] + bv.w);
        *(float4*)&y1[row * O1 + tc * 4] = o;
    }
}

__global__ __launch_bounds__(128) void k_stats1(const float* __restrict__ y,
                                                float* __restrict__ ps,
                                                float* __restrict__ pq) {
    const int t = threadIdx.x;
    const int r0 = blockIdx.x * 256;
    float s = 0.0f, q = 0.0f;
    for (int r = 0; r < 256; ++r) {
        float v = y[(size_t)(r0 + r) * O1 + t];
        s += v;
        q = fmaf(v, v, q);
    }
    ps[blockIdx.x * O1 + t] = s;
    pq[blockIdx.x * O1 + t] = q;
}

__global__ __launch_bounds__(128) void k_fin1(const float* __restrict__ ps,
                                              const float* __restrict__ pq,
                                              const float* __restrict__ gamma,
                                              const float* __restrict__ beta,
                                              float* __restrict__ sc,
                                              float* __restrict__ sh) {
    const int c = threadIdx.x;
    float s = 0.0f, q = 0.0f;
    for (int b = 0; b < 256; ++b) { s += ps[b * O1 + c]; q += pq[b * O1 + c]; }
    const float mean = s * (1.0f / NROWS);
    const float var = q * (1.0f / NROWS) - mean * mean;
    const float rs = rsqrtf(var + 1e-5f);
    const float scale = gamma[c] * rs;
    sc[c] = scale;
    sh[c] = beta[c] - mean * scale;
}

// In-place BN + ReLU on d_out (one float4 per thread).
__global__ __launch_bounds__(256) void k_bnrelu(float* __restrict__ y,
                                                const float* __restrict__ sc,
                                                const float* __restrict__ sh) {
    const int e4 = blockIdx.x * 256 + threadIdx.x;
    const int c = (e4 & 31) << 2;  // channel of first lane elem (O1=128)
    float4 v = *(float4*)&y[(size_t)e4 * 4];
    const float4 s4 = *(const float4*)&sc[c];
    const float4 h4 = *(const float4*)&sh[c];
    v.x = fmaxf(fmaf(v.x, s4.x, h4.x), 0.0f);
    v.y = fmaxf(fmaf(v.y, s4.y, h4.y), 0.0f);
    v.z = fmaxf(fmaf(v.z, s4.z, h4.z), 0.0f);
    v.w = fmaxf(fmaf(v.w, s4.w, h4.w), 0.0f);
    *(float4*)&y[(size_t)e4 * 4] = v;
}

// ---------------------------------------------------------------------------
extern "C" void kernel_launch(void* const* d_in, const int* in_sizes, int n_in,
                              void* d_out, int out_size, void* d_ws, size_t ws_size,
                              hipStream_t stream) {
    const float* xyz1    = (const float*)d_in[0];
    const float* xyz2    = (const float*)d_in[1];
    const float* points1 = (const float*)d_in[2];
    const float* points2 = (const float*)d_in[3];
    const float* W0      = (const float*)d_in[4];
    const float* b0      = (const float*)d_in[5];
    const float* gamma0  = (const float*)d_in[6];
    const float* beta0   = (const float*)d_in[7];
    const float* W1      = (const float*)d_in[8];
    const float* b1      = (const float*)d_in[9];
    const float* gamma1  = (const float*)d_in[10];
    const float* beta1   = (const float*)d_in[11];
    float* out = (float*)d_out;

    char* ws = (char*)d_ws;
    float* x   = (float*)(ws + 0);                 // 100,663,296 B
    float* y0  = (float*)(ws + 100663296ull);      //  67,108,864 B
    int*  idxb = (int*)  (ws + 167772160ull);      //     786,432 B
    float* wb  = (float*)(ws + 168558592ull);      //     786,432 B
    float* W0t = (float*)(ws + 169345024ull);      //     393,216 B
    float* W1t = (float*)(ws + 169738240ull);      //     131,072 B
    float* ps0 = (float*)(ws + 169869312ull);      //     262,144 B
    float* pq0 = (float*)(ws + 170131456ull);      //     262,144 B
    float* ps1 = (float*)(ws + 170393600ull);      //     131,072 B
    float* pq1 = (float*)(ws + 170524672ull);      //     131,072 B
    float* sc0 = (float*)(ws + 170655744ull);
    float* sh0 = (float*)(ws + 170656768ull);
    float* sc1 = (float*)(ws + 170657792ull);
    float* sh1 = (float*)(ws + 170658304ull);

    hipLaunchKernelGGL(k_tr, dim3(512), dim3(256), 0, stream, W0, W1, W0t, W1t);
    hipLaunchKernelGGL(k_knn, dim3(256), dim3(256), 0, stream, xyz1, xyz2, idxb, wb);
    hipLaunchKernelGGL(k_interp, dim3(NROWS / 8), dim3(384), 0, stream,
                       points1, points2, idxb, wb, x);
    hipLaunchKernelGGL(k_gemm0, dim3(NROWS / 64), dim3(256), 0, stream,
                       x, W0t, b0, y0);
    hipLaunchKernelGGL(k_stats0, dim3(256), dim3(256), 0, stream, y0, ps0, pq0);
    hipLaunchKernelGGL(k_fin0, dim3(1), dim3(256), 0, stream,
                       ps0, pq0, gamma0, beta0, sc0, sh0);
    hipLaunchKernelGGL(k_gemm1, dim3(NROWS / 64), dim3(256), 0, stream,
                       y0, W1t, b1, sc0, sh0, out);
    hipLaunchKernelGGL(k_stats1, dim3(256), dim3(128), 0, stream, out, ps1, pq1);
    hipLaunchKernelGGL(k_fin1, dim3(1), dim3(128), 0, stream,
                       ps1, pq1, gamma1, beta1, sc1, sh1);
    hipLaunchKernelGGL(k_bnrelu, dim3(NROWS * O1 / 4 / 256), dim3(256), 0, stream,
                       out, sc1, sh1);
}

// Round 2
// 366.790 us; speedup vs baseline: 1.3058x; 1.3058x over previous
//
#include <hip/hip_runtime.h>
#include <cstdint>
#include <cstddef>

#define BATCH 8
#define NPTS  8192
#define MPTS  2048
#define C1    128
#define C2    256
#define K0    384   // C1 + C2
#define O0    256
#define O1    128
#define NROWS (BATCH * NPTS)  // 65536

// ---------------------------------------------------------------------------
// Kernel 1: brute-force 3-NN + inverse-distance weights.
// Block = 64 queries x 4 segment-scanner threads (256 thr). xyz2 of the batch
// cached in LDS as float4 (x,y,z,|p|^2). Each thread scans a 512-point
// segment, keeping a partial top-3; the 4 partials (12 candidates, in
// ascending global-index order) merge with strict-< insertion, matching
// stable top_k tie behavior. Distance arithmetic replicates the reference
// ( -2*dot + |x|^2 + |y|^2, left-assoc, no FMA contraction ).
// Grid = 1024 blocks -> 4 blocks/CU, 16 waves/CU (vs 1 wave/SIMD before).
// ---------------------------------------------------------------------------
__global__ __launch_bounds__(256) void k_knn(const float* __restrict__ xyz1,
                                             const float* __restrict__ xyz2,
                                             int* __restrict__ idxo,
                                             float* __restrict__ wo) {
    __shared__ float4 s2[MPTS];     // 32 KB
    __shared__ float cd[64][13];    // 12 candidates + pad (13 odd -> no conflict)
    __shared__ int   ci[64][13];

    const int b = blockIdx.x >> 7;             // 128 blocks per batch
    const int qbase = (blockIdx.x & 127) * 64;

    for (int p = threadIdx.x; p < MPTS; p += 256) {
        const size_t src = ((size_t)b * MPTS + p) * 3;
        float px = xyz2[src + 0], py = xyz2[src + 1], pz = xyz2[src + 2];
        float sy = __fadd_rn(__fadd_rn(__fmul_rn(px, px), __fmul_rn(py, py)),
                             __fmul_rn(pz, pz));
        s2[p] = make_float4(px, py, pz, sy);
    }
    __syncthreads();

    const int q   = threadIdx.x >> 2;   // 0..63
    const int seg = threadIdx.x & 3;    // 0..3
    const int n = qbase + q;
    const size_t qoff = ((size_t)b * NPTS + n) * 3;
    const float qx = xyz1[qoff + 0], qy = xyz1[qoff + 1], qz = xyz1[qoff + 2];
    const float sx = __fadd_rn(__fadd_rn(__fmul_rn(qx, qx), __fmul_rn(qy, qy)),
                               __fmul_rn(qz, qz));

    float d0 = 3.0e38f, d1 = 3.0e38f, d2 = 3.0e38f;
    int i0 = 0, i1 = 0, i2 = 0;
    const int m0 = seg * (MPTS / 4);
#pragma unroll 8
    for (int mm = 0; mm < MPTS / 4; ++mm) {
        const int m = m0 + mm;
        float4 pp = s2[m];
        float dot = __fadd_rn(__fadd_rn(__fmul_rn(qx, pp.x), __fmul_rn(qy, pp.y)),
                              __fmul_rn(qz, pp.z));
        float d = __fadd_rn(__fadd_rn(__fmul_rn(-2.0f, dot), sx), pp.w);
        if (d < d2) {
            if (d < d1) {
                d2 = d1; i2 = i1;
                if (d < d0) { d1 = d0; i1 = i0; d0 = d; i0 = m; }
                else        { d1 = d;  i1 = m; }
            } else { d2 = d; i2 = m; }
        }
    }
    cd[q][seg * 3 + 0] = d0; ci[q][seg * 3 + 0] = i0;
    cd[q][seg * 3 + 1] = d1; ci[q][seg * 3 + 1] = i1;
    cd[q][seg * 3 + 2] = d2; ci[q][seg * 3 + 2] = i2;
    __syncthreads();

    if (threadIdx.x < 64) {
        const int qq = threadIdx.x;
        float D0 = 3.0e38f, D1 = 3.0e38f, D2 = 3.0e38f;
        int I0 = 0, I1 = 0, I2 = 0;
#pragma unroll
        for (int j = 0; j < 12; ++j) {
            const float d = cd[qq][j];
            const int   i = ci[qq][j];
            if (d < D2) {
                if (d < D1) {
                    D2 = D1; I2 = I1;
                    if (d < D0) { D1 = D0; I1 = I0; D0 = d; I0 = i; }
                    else        { D1 = d;  I1 = i; }
                } else { D2 = d; I2 = i; }
            }
        }
        const float r0 = 1.0f / __fadd_rn(D0, 1e-8f);
        const float r1 = 1.0f / __fadd_rn(D1, 1e-8f);
        const float r2 = 1.0f / __fadd_rn(D2, 1e-8f);
        const float norm = __fadd_rn(__fadd_rn(r0, r1), r2);

        const size_t row = (size_t)b * NPTS + qbase + qq;
        idxo[row * 3 + 0] = I0; idxo[row * 3 + 1] = I1; idxo[row * 3 + 2] = I2;
        wo[row * 3 + 0] = r0 / norm;
        wo[row * 3 + 1] = r1 / norm;
        wo[row * 3 + 2] = r2 / norm;
    }
}

// ---------------------------------------------------------------------------
// Kernel 2: gather + interpolate + concat -> x[65536][384]
// block = 384 threads (one output column each), 8 rows per block.
// ---------------------------------------------------------------------------
__global__ __launch_bounds__(384) void k_interp(const float* __restrict__ p1,
                                                const float* __restrict__ p2,
                                                const int* __restrict__ idx,
                                                const float* __restrict__ w,
                                                float* __restrict__ x) {
    const int t = threadIdx.x;
    const int row0 = blockIdx.x * 8;
#pragma unroll
    for (int r = 0; r < 8; ++r) {
        const int row = row0 + r;
        const int b = row >> 13;  // / NPTS
        const int i0 = idx[row * 3 + 0];
        const int i1 = idx[row * 3 + 1];
        const int i2 = idx[row * 3 + 2];
        const float w0 = w[row * 3 + 0];
        const float w1 = w[row * 3 + 1];
        const float w2 = w[row * 3 + 2];
        float v;
        if (t < C1) {
            v = p1[(size_t)row * C1 + t];
        } else {
            const int cc = t - C1;
            const size_t base = (size_t)b * MPTS * C2;
            v = w0 * p2[base + (size_t)i0 * C2 + cc]
              + w1 * p2[base + (size_t)i1 * C2 + cc]
              + w2 * p2[base + (size_t)i2 * C2 + cc];
        }
        x[(size_t)row * K0 + t] = v;
    }
}

// ---------------------------------------------------------------------------
// Small transpose: W0[256][384] -> W0t[384][256], W1[128][256] -> W1t[256][128]
// ---------------------------------------------------------------------------
__global__ __launch_bounds__(256) void k_tr(const float* __restrict__ W0,
                                            const float* __restrict__ W1,
                                            float* __restrict__ W0t,
                                            float* __restrict__ W1t) {
    const int e = blockIdx.x * 256 + threadIdx.x;
    if (e < O0 * K0) {
        const int k = e >> 8, o = e & 255;
        W0t[e] = W0[o * K0 + k];
    }
    const int e2 = e - O0 * K0;
    if (e2 >= 0 && e2 < O1 * O0) {
        const int k = e2 >> 7, o = e2 & 127;
        W1t[e2] = W1[o * O0 + k];
    }
}

// ---------------------------------------------------------------------------
// GEMM0: y0[65536][256] = x[65536][384] @ W0t + b0   (pre-BN output)
// BM=64 BN=256 BK=16, 256 threads, 8x8 microtile (cols split tc*4 / tc*4+128).
// ---------------------------------------------------------------------------
__global__ __launch_bounds__(256) void k_gemm0(const float* __restrict__ x,
                                               const float* __restrict__ Wt,
                                               const float* __restrict__ bias,
                                               float* __restrict__ y) {
    __shared__ float As[16][68];   // [k][row], padded
    __shared__ float Bs[16][256];  // [k][col]
    const int t = threadIdx.x;
    const int r0 = blockIdx.x * 64;
    const int tr = t >> 5;        // 0..7  -> 8 rows
    const int tc = t & 31;        // 0..31 -> 4+4 cols
    const int lr = t >> 2;        // 0..63
    const int lk4 = (t & 3) << 2; // 0,4,8,12

    float acc[8][8];
#pragma unroll
    for (int i = 0; i < 8; ++i)
#pragma unroll
        for (int j = 0; j < 8; ++j) acc[i][j] = 0.0f;

    for (int kt = 0; kt < K0; kt += 16) {
        float4 av = *(const float4*)&x[(size_t)(r0 + lr) * K0 + kt + lk4];
        As[lk4 + 0][lr] = av.x;
        As[lk4 + 1][lr] = av.y;
        As[lk4 + 2][lr] = av.z;
        As[lk4 + 3][lr] = av.w;
        {
            const int kk = t >> 4;         // 0..15
            const int c4 = (t & 15) << 4;  // 0..240
            const float4* src = (const float4*)&Wt[(size_t)(kt + kk) * O0 + c4];
            float4* dst = (float4*)&Bs[kk][c4];
            dst[0] = src[0]; dst[1] = src[1]; dst[2] = src[2]; dst[3] = src[3];
        }
        __syncthreads();
#pragma unroll
        for (int kk = 0; kk < 16; ++kk) {
            float a[8], b[8];
            *(float4*)&a[0] = *(const float4*)&As[kk][tr * 8];
            *(float4*)&a[4] = *(const float4*)&As[kk][tr * 8 + 4];
            *(float4*)&b[0] = *(const float4*)&Bs[kk][tc * 4];
            *(float4*)&b[4] = *(const float4*)&Bs[kk][tc * 4 + 128];
#pragma unroll
            for (int i = 0; i < 8; ++i)
#pragma unroll
                for (int j = 0; j < 8; ++j)
                    acc[i][j] = fmaf(a[i], b[j], acc[i][j]);
        }
        __syncthreads();
    }

    const float4 b0v = *(const float4*)&bias[tc * 4];
    const float4 b1v = *(const float4*)&bias[tc * 4 + 128];
#pragma unroll
    for (int i = 0; i < 8; ++i) {
        const size_t row = (size_t)(r0 + tr * 8 + i);
        float4 o0 = make_float4(acc[i][0] + b0v.x, acc[i][1] + b0v.y,
                                acc[i][2] + b0v.z, acc[i][3] + b0v.w);
        float4 o1 = make_float4(acc[i][4] + b1v.x, acc[i][5] + b1v.y,
                                acc[i][6] + b1v.z, acc[i][7] + b1v.w);
        *(float4*)&y[row * O0 + tc * 4] = o0;
        *(float4*)&y[row * O0 + tc * 4 + 128] = o1;
    }
}

// ---------------------------------------------------------------------------
// Column stats (deterministic two-stage): per-block partial sum/sumsq.
// ---------------------------------------------------------------------------
__global__ __launch_bounds__(256) void k_stats0(const float* __restrict__ y,
                                                float* __restrict__ ps,
                                                float* __restrict__ pq) {
    const int t = threadIdx.x;
    const int r0 = blockIdx.x * 256;
    float s = 0.0f, q = 0.0f;
    for (int r = 0; r < 256; ++r) {
        float v = y[(size_t)(r0 + r) * O0 + t];
        s += v;
        q = fmaf(v, v, q);
    }
    ps[blockIdx.x * O0 + t] = s;
    pq[blockIdx.x * O0 + t] = q;
}

__global__ __launch_bounds__(256) void k_fin0(const float* __restrict__ ps,
                                              const float* __restrict__ pq,
                                              const float* __restrict__ gamma,
                                              const float* __restrict__ beta,
                                              float* __restrict__ sc,
                                              float* __restrict__ sh) {
    const int c = threadIdx.x;
    float s = 0.0f, q = 0.0f;
    for (int b = 0; b < 256; ++b) { s += ps[b * O0 + c]; q += pq[b * O0 + c]; }
    const float mean = s * (1.0f / NROWS);
    const float var = q * (1.0f / NROWS) - mean * mean;
    const float rs = rsqrtf(var + 1e-5f);
    const float scale = gamma[c] * rs;
    sc[c] = scale;
    sh[c] = beta[c] - mean * scale;
}

// ---------------------------------------------------------------------------
// GEMM1: out_pre[65536][128] = relu(BN0(y0)) @ W1t + b1  (BN0 fused on load)
// BM=64 BN=128 BK=16, 256 threads, 8x4 microtile.  Writes pre-BN y1 to d_out.
// ---------------------------------------------------------------------------
__global__ __launch_bounds__(256) void k_gemm1(const float* __restrict__ y0,
                                               const float* __restrict__ Wt,
                                               const float* __restrict__ bias,
                                               const float* __restrict__ sc,
                                               const float* __restrict__ sh,
                                               float* __restrict__ y1) {
    __shared__ float As[16][68];
    __shared__ float Bs[16][128];
    const int t = threadIdx.x;
    const int r0 = blockIdx.x * 64;
    const int tr = t >> 5;        // 0..7
    const int tc = t & 31;        // 0..31 -> cols tc*4..+3
    const int lr = t >> 2;
    const int lk4 = (t & 3) << 2;

    float acc[8][4];
#pragma unroll
    for (int i = 0; i < 8; ++i)
#pragma unroll
        for (int j = 0; j < 4; ++j) acc[i][j] = 0.0f;

    for (int kt = 0; kt < O0; kt += 16) {
        const int c = kt + lk4;
        float4 av = *(const float4*)&y0[(size_t)(r0 + lr) * O0 + c];
        av.x = fmaxf(fmaf(av.x, sc[c + 0], sh[c + 0]), 0.0f);
        av.y = fmaxf(fmaf(av.y, sc[c + 1], sh[c + 1]), 0.0f);
        av.z = fmaxf(fmaf(av.z, sc[c + 2], sh[c + 2]), 0.0f);
        av.w = fmaxf(fmaf(av.w, sc[c + 3], sh[c + 3]), 0.0f);
        As[lk4 + 0][lr] = av.x;
        As[lk4 + 1][lr] = av.y;
        As[lk4 + 2][lr] = av.z;
        As[lk4 + 3][lr] = av.w;
        {
            const int kk = t >> 4;        // 0..15
            const int c8 = (t & 15) << 3; // 0..120
            const float4* src = (const float4*)&Wt[(size_t)(kt + kk) * O1 + c8];
            float4* dst = (float4*)&Bs[kk][c8];
            dst[0] = src[0]; dst[1] = src[1];
        }
        __syncthreads();
#pragma unroll
        for (int kk = 0; kk < 16; ++kk) {
            float a[8], b[4];
            *(float4*)&a[0] = *(const float4*)&As[kk][tr * 8];
            *(float4*)&a[4] = *(const float4*)&As[kk][tr * 8 + 4];
            *(float4*)&b[0] = *(const float4*)&Bs[kk][tc * 4];
#pragma unroll
            for (int i = 0; i < 8; ++i)
#pragma unroll
                for (int j = 0; j < 4; ++j)
                    acc[i][j] = fmaf(a[i], b[j], acc[i][j]);
        }
        __syncthreads();
    }

    const float4 bv = *(const float4*)&bias[tc * 4];
#pragma unroll
    for (int i = 0; i < 8; ++i) {
        const size_t row = (size_t)(r0 + tr * 8 + i);
        float4 o = make_float4(acc[i][0] + bv.x, acc[i][1] + bv.y,
                               acc[i][2] + bv.z, acc[i][3] + bv.w);
        *(float4*)&y1[row * O1 + tc * 4] = o;
    }
}

__global__ __launch_bounds__(128) void k_stats1(const float* __restrict__ y,
                                                float* __restrict__ ps,
                                                float* __restrict__ pq) {
    const int t = threadIdx.x;
    const int r0 = blockIdx.x * 256;
    float s = 0.0f, q = 0.0f;
    for (int r = 0; r < 256; ++r) {
        float v = y[(size_t)(r0 + r) * O1 + t];
        s += v;
        q = fmaf(v, v, q);
    }
    ps[blockIdx.x * O1 + t] = s;
    pq[blockIdx.x * O1 + t] = q;
}

__global__ __launch_bounds__(128) void k_fin1(const float* __restrict__ ps,
                                              const float* __restrict__ pq,
                                              const float* __restrict__ gamma,
                                              const float* __restrict__ beta,
                                              float* __restrict__ sc,
                                              float* __restrict__ sh) {
    const int c = threadIdx.x;
    float s = 0.0f, q = 0.0f;
    for (int b = 0; b < 256; ++b) { s += ps[b * O1 + c]; q += pq[b * O1 + c]; }
    const float mean = s * (1.0f / NROWS);
    const float var = q * (1.0f / NROWS) - mean * mean;
    const float rs = rsqrtf(var + 1e-5f);
    const float scale = gamma[c] * rs;
    sc[c] = scale;
    sh[c] = beta[c] - mean * scale;
}

// In-place BN + ReLU on d_out (one float4 per thread).
__global__ __launch_bounds__(256) void k_bnrelu(float* __restrict__ y,
                                                const float* __restrict__ sc,
                                                const float* __restrict__ sh) {
    const int e4 = blockIdx.x * 256 + threadIdx.x;
    const int c = (e4 & 31) << 2;  // channel of first lane elem (O1=128)
    float4 v = *(float4*)&y[(size_t)e4 * 4];
    const float4 s4 = *(const float4*)&sc[c];
    const float4 h4 = *(const float4*)&sh[c];
    v.x = fmaxf(fmaf(v.x, s4.x, h4.x), 0.0f);
    v.y = fmaxf(fmaf(v.y, s4.y, h4.y), 0.0f);
    v.z = fmaxf(fmaf(v.z, s4.z, h4.z), 0.0f);
    v.w = fmaxf(fmaf(v.w, s4.w, h4.w), 0.0f);
    *(float4*)&y[(size_t)e4 * 4] = v;
}

// ---------------------------------------------------------------------------
extern "C" void kernel_launch(void* const* d_in, const int* in_sizes, int n_in,
                              void* d_out, int out_size, void* d_ws, size_t ws_size,
                              hipStream_t stream) {
    const float* xyz1    = (const float*)d_in[0];
    const float* xyz2    = (const float*)d_in[1];
    const float* points1 = (const float*)d_in[2];
    const float* points2 = (const float*)d_in[3];
    const float* W0      = (const float*)d_in[4];
    const float* b0      = (const float*)d_in[5];
    const float* gamma0  = (const float*)d_in[6];
    const float* beta0   = (const float*)d_in[7];
    const float* W1      = (const float*)d_in[8];
    const float* b1      = (const float*)d_in[9];
    const float* gamma1  = (const float*)d_in[10];
    const float* beta1   = (const float*)d_in[11];
    float* out = (float*)d_out;

    char* ws = (char*)d_ws;
    float* x   = (float*)(ws + 0);                 // 100,663,296 B
    float* y0  = (float*)(ws + 100663296ull);      //  67,108,864 B
    int*  idxb = (int*)  (ws + 167772160ull);      //     786,432 B
    float* wb  = (float*)(ws + 168558592ull);      //     786,432 B
    float* W0t = (float*)(ws + 169345024ull);      //     393,216 B
    float* W1t = (float*)(ws + 169738240ull);      //     131,072 B
    float* ps0 = (float*)(ws + 169869312ull);      //     262,144 B
    float* pq0 = (float*)(ws + 170131456ull);      //     262,144 B
    float* ps1 = (float*)(ws + 170393600ull);      //     131,072 B
    float* pq1 = (float*)(ws + 170524672ull);      //     131,072 B
    float* sc0 = (float*)(ws + 170655744ull);
    float* sh0 = (float*)(ws + 170656768ull);
    float* sc1 = (float*)(ws + 170657792ull);
    float* sh1 = (float*)(ws + 170658304ull);

    hipLaunchKernelGGL(k_tr, dim3(512), dim3(256), 0, stream, W0, W1, W0t, W1t);
    hipLaunchKernelGGL(k_knn, dim3(1024), dim3(256), 0, stream, xyz1, xyz2, idxb, wb);
    hipLaunchKernelGGL(k_interp, dim3(NROWS / 8), dim3(384), 0, stream,
                       points1, points2, idxb, wb, x);
    hipLaunchKernelGGL(k_gemm0, dim3(NROWS / 64), dim3(256), 0, stream,
                       x, W0t, b0, y0);
    hipLaunchKernelGGL(k_stats0, dim3(256), dim3(256), 0, stream, y0, ps0, pq0);
    hipLaunchKernelGGL(k_fin0, dim3(1), dim3(256), 0, stream,
                       ps0, pq0, gamma0, beta0, sc0, sh0);
    hipLaunchKernelGGL(k_gemm1, dim3(NROWS / 64), dim3(256), 0, stream,
                       y0, W1t, b1, sc0, sh0, out);
    hipLaunchKernelGGL(k_stats1, dim3(256), dim3(128), 0, stream, out, ps1, pq1);
    hipLaunchKernelGGL(k_fin1, dim3(1), dim3(128), 0, stream,
                       ps1, pq1, gamma1, beta1, sc1, sh1);
    hipLaunchKernelGGL(k_bnrelu, dim3(NROWS * O1 / 4 / 256), dim3(256), 0, stream,
                       out, sc1, sh1);
}

// Round 3
// 212.008 us; speedup vs baseline: 2.2591x; 1.7301x over previous
//
#include <hip/hip_runtime.h>
#include <cstdint>
#include <cstddef>

#define BATCH 8
#define NPTS  8192
#define MPTS  2048
#define C1    128
#define C2    256
#define K0    384   // C1 + C2
#define O0    256
#define O1    128
#define NROWS (BATCH * NPTS)  // 65536

typedef __attribute__((ext_vector_type(8))) short bf16x8;
typedef __attribute__((ext_vector_type(4))) float f32x4;

__device__ __forceinline__ unsigned short f2b(float f) {
    union { float f; unsigned int u; } v; v.f = f;
    unsigned int u = v.u + 0x7FFFu + ((v.u >> 16) & 1u);  // RNE
    return (unsigned short)(u >> 16);
}
__device__ __forceinline__ float b2f(unsigned short h) {
    union { unsigned int u; float f; } v; v.u = ((unsigned int)h) << 16; return v.f;
}
__device__ __forceinline__ unsigned int pack2(float a, float b) {
    return (unsigned int)f2b(a) | ((unsigned int)f2b(b) << 16);
}

// ---------------------------------------------------------------------------
// Kernel 1: brute-force 3-NN + inverse-distance weights. (unchanged from R1)
// ---------------------------------------------------------------------------
__global__ __launch_bounds__(256) void k_knn(const float* __restrict__ xyz1,
                                             const float* __restrict__ xyz2,
                                             int* __restrict__ idxo,
                                             float* __restrict__ wo) {
    __shared__ float4 s2[MPTS];     // 32 KB
    __shared__ float cd[64][13];
    __shared__ int   ci[64][13];

    const int b = blockIdx.x >> 7;
    const int qbase = (blockIdx.x & 127) * 64;

    for (int p = threadIdx.x; p < MPTS; p += 256) {
        const size_t src = ((size_t)b * MPTS + p) * 3;
        float px = xyz2[src + 0], py = xyz2[src + 1], pz = xyz2[src + 2];
        float sy = __fadd_rn(__fadd_rn(__fmul_rn(px, px), __fmul_rn(py, py)),
                             __fmul_rn(pz, pz));
        s2[p] = make_float4(px, py, pz, sy);
    }
    __syncthreads();

    const int q   = threadIdx.x >> 2;
    const int seg = threadIdx.x & 3;
    const int n = qbase + q;
    const size_t qoff = ((size_t)b * NPTS + n) * 3;
    const float qx = xyz1[qoff + 0], qy = xyz1[qoff + 1], qz = xyz1[qoff + 2];
    const float sx = __fadd_rn(__fadd_rn(__fmul_rn(qx, qx), __fmul_rn(qy, qy)),
                               __fmul_rn(qz, qz));

    float d0 = 3.0e38f, d1 = 3.0e38f, d2 = 3.0e38f;
    int i0 = 0, i1 = 0, i2 = 0;
    const int m0 = seg * (MPTS / 4);
#pragma unroll 8
    for (int mm = 0; mm < MPTS / 4; ++mm) {
        const int m = m0 + mm;
        float4 pp = s2[m];
        float dot = __fadd_rn(__fadd_rn(__fmul_rn(qx, pp.x), __fmul_rn(qy, pp.y)),
                              __fmul_rn(qz, pp.z));
        float d = __fadd_rn(__fadd_rn(__fmul_rn(-2.0f, dot), sx), pp.w);
        if (d < d2) {
            if (d < d1) {
                d2 = d1; i2 = i1;
                if (d < d0) { d1 = d0; i1 = i0; d0 = d; i0 = m; }
                else        { d1 = d;  i1 = m; }
            } else { d2 = d; i2 = m; }
        }
    }
    cd[q][seg * 3 + 0] = d0; ci[q][seg * 3 + 0] = i0;
    cd[q][seg * 3 + 1] = d1; ci[q][seg * 3 + 1] = i1;
    cd[q][seg * 3 + 2] = d2; ci[q][seg * 3 + 2] = i2;
    __syncthreads();

    if (threadIdx.x < 64) {
        const int qq = threadIdx.x;
        float D0 = 3.0e38f, D1 = 3.0e38f, D2 = 3.0e38f;
        int I0 = 0, I1 = 0, I2 = 0;
#pragma unroll
        for (int j = 0; j < 12; ++j) {
            const float d = cd[qq][j];
            const int   i = ci[qq][j];
            if (d < D2) {
                if (d < D1) {
                    D2 = D1; I2 = I1;
                    if (d < D0) { D1 = D0; I1 = I0; D0 = d; I0 = i; }
                    else        { D1 = d;  I1 = i; }
                } else { D2 = d; I2 = i; }
            }
        }
        const float r0 = 1.0f / __fadd_rn(D0, 1e-8f);
        const float r1 = 1.0f / __fadd_rn(D1, 1e-8f);
        const float r2 = 1.0f / __fadd_rn(D2, 1e-8f);
        const float norm = __fadd_rn(__fadd_rn(r0, r1), r2);

        const size_t row = (size_t)b * NPTS + qbase + qq;
        idxo[row * 3 + 0] = I0; idxo[row * 3 + 1] = I1; idxo[row * 3 + 2] = I2;
        wo[row * 3 + 0] = r0 / norm;
        wo[row * 3 + 1] = r1 / norm;
        wo[row * 3 + 2] = r2 / norm;
    }
}

// ---------------------------------------------------------------------------
// Kernel 2: gather + interpolate + concat -> x[65536][384] (bf16 now)
// ---------------------------------------------------------------------------
__global__ __launch_bounds__(384) void k_interp(const float* __restrict__ p1,
                                                const float* __restrict__ p2,
                                                const int* __restrict__ idx,
                                                const float* __restrict__ w,
                                                unsigned short* __restrict__ x) {
    const int t = threadIdx.x;
    const int row0 = blockIdx.x * 8;
#pragma unroll
    for (int r = 0; r < 8; ++r) {
        const int row = row0 + r;
        const int b = row >> 13;
        const int i0 = idx[row * 3 + 0];
        const int i1 = idx[row * 3 + 1];
        const int i2 = idx[row * 3 + 2];
        const float w0 = w[row * 3 + 0];
        const float w1 = w[row * 3 + 1];
        const float w2 = w[row * 3 + 2];
        float v;
        if (t < C1) {
            v = p1[(size_t)row * C1 + t];
        } else {
            const int cc = t - C1;
            const size_t base = (size_t)b * MPTS * C2;
            v = w0 * p2[base + (size_t)i0 * C2 + cc]
              + w1 * p2[base + (size_t)i1 * C2 + cc]
              + w2 * p2[base + (size_t)i2 * C2 + cc];
        }
        x[(size_t)row * K0 + t] = f2b(v);
    }
}

// ---------------------------------------------------------------------------
// Weight conversion fp32 -> bf16 (row-major [O][K] kept: that IS the B^T
// contiguous-k layout the MFMA B-fragment wants).
// ---------------------------------------------------------------------------
__global__ __launch_bounds__(256) void k_cvt(const float* __restrict__ W0,
                                             const float* __restrict__ W1,
                                             unsigned short* __restrict__ Wb0,
                                             unsigned short* __restrict__ Wb1) {
    const int e = blockIdx.x * 256 + threadIdx.x;
    if (e < O0 * K0) Wb0[e] = f2b(W0[e]);
    const int e2 = e - O0 * K0;
    if (e2 >= 0 && e2 < O1 * O0) Wb1[e2] = f2b(W1[e2]);
}

// ---------------------------------------------------------------------------
// GEMM0 (MFMA bf16): y0[65536][256] = x @ W0^T + b0, stored bf16 (pre-BN).
// Block tile 128x128 (grid 512 x 2), 256 thr = 4 waves (2x2), wave 64x64.
// BK=64; LDS As/Bs [128 rows][64 bf16] with XOR swizzle slot^=(row&7)
// on ds_write AND ds_read (both-sides rule).
// ---------------------------------------------------------------------------
__global__ __launch_bounds__(256) void k_gemm0(const unsigned short* __restrict__ x,
                                               const unsigned short* __restrict__ Wb,
                                               const float* __restrict__ bias,
                                               unsigned short* __restrict__ y) {
    __shared__ __align__(16) unsigned short As[128 * 64];
    __shared__ __align__(16) unsigned short Bs[128 * 64];
    const int t = threadIdx.x;
    const int r0 = blockIdx.x * 128;
    const int n0 = blockIdx.y * 128;
    const int lane = t & 63;
    const int wm = (t >> 6) & 1;
    const int wn = (t >> 6) >> 1;
    const int row_s = t >> 1;          // staging row 0..127
    const int slot4 = (t & 1) * 4;     // staging slot base
    const int sw = row_s & 7;

    const unsigned short* aptr = x  + (size_t)(r0 + row_s) * K0;
    const unsigned short* bptr = Wb + (size_t)(n0 + row_s) * K0;
    unsigned short* asw = &As[row_s * 64];
    unsigned short* bsw = &Bs[row_s * 64];

    f32x4 zero = {0.f, 0.f, 0.f, 0.f};
    f32x4 acc[4][4];
#pragma unroll
    for (int i = 0; i < 4; ++i)
#pragma unroll
        for (int j = 0; j < 4; ++j) acc[i][j] = zero;

    for (int kt = 0; kt < K0; kt += 64) {
#pragma unroll
        for (int i = 0; i < 4; ++i) {
            const int slot = slot4 + i;
            const int ssw = slot ^ sw;
            uint4 av = *(const uint4*)(aptr + kt + slot * 8);
            uint4 bv = *(const uint4*)(bptr + kt + slot * 8);
            *(uint4*)(asw + ssw * 8) = av;
            *(uint4*)(bsw + ssw * 8) = bv;
        }
        __syncthreads();
#pragma unroll
        for (int ks = 0; ks < 2; ++ks) {
            bf16x8 af[4], bfr[4];
#pragma unroll
            for (int fr = 0; fr < 4; ++fr) {
                const int row = wm * 64 + fr * 16 + (lane & 15);
                const int slot = (ks * 4 + (lane >> 4)) ^ (row & 7);
                af[fr] = *(const bf16x8*)&As[row * 64 + slot * 8];
            }
#pragma unroll
            for (int fc = 0; fc < 4; ++fc) {
                const int row = wn * 64 + fc * 16 + (lane & 15);
                const int slot = (ks * 4 + (lane >> 4)) ^ (row & 7);
                bfr[fc] = *(const bf16x8*)&Bs[row * 64 + slot * 8];
            }
#pragma unroll
            for (int fr = 0; fr < 4; ++fr)
#pragma unroll
                for (int fc = 0; fc < 4; ++fc)
                    acc[fr][fc] = __builtin_amdgcn_mfma_f32_16x16x32_bf16(
                        af[fr], bfr[fc], acc[fr][fc], 0, 0, 0);
        }
        __syncthreads();
    }

#pragma unroll
    for (int fc = 0; fc < 4; ++fc) {
        const int n = n0 + wn * 64 + fc * 16 + (lane & 15);
        const float bv = bias[n];
#pragma unroll
        for (int fr = 0; fr < 4; ++fr) {
#pragma unroll
            for (int j = 0; j < 4; ++j) {
                const int m = r0 + wm * 64 + fr * 16 + (lane >> 4) * 4 + j;
                y[(size_t)m * O0 + n] = f2b(acc[fr][fc][j] + bv);
            }
        }
    }
}

// ---------------------------------------------------------------------------
// Column stats over bf16 y0.
// ---------------------------------------------------------------------------
__global__ __launch_bounds__(256) void k_stats0(const unsigned short* __restrict__ y,
                                                float* __restrict__ ps,
                                                float* __restrict__ pq) {
    const int t = threadIdx.x;
    const int r0 = blockIdx.x * 256;
    float s = 0.0f, q = 0.0f;
    for (int r = 0; r < 256; ++r) {
        float v = b2f(y[(size_t)(r0 + r) * O0 + t]);
        s += v;
        q = fmaf(v, v, q);
    }
    ps[blockIdx.x * O0 + t] = s;
    pq[blockIdx.x * O0 + t] = q;
}

__global__ __launch_bounds__(256) void k_fin0(const float* __restrict__ ps,
                                              const float* __restrict__ pq,
                                              const float* __restrict__ gamma,
                                              const float* __restrict__ beta,
                                              float* __restrict__ sc,
                                              float* __restrict__ sh) {
    const int c = threadIdx.x;
    float s = 0.0f, q = 0.0f;
    for (int b = 0; b < 256; ++b) { s += ps[b * O0 + c]; q += pq[b * O0 + c]; }
    const float mean = s * (1.0f / NROWS);
    const float var = q * (1.0f / NROWS) - mean * mean;
    const float rs = rsqrtf(var + 1e-5f);
    const float scale = gamma[c] * rs;
    sc[c] = scale;
    sh[c] = beta[c] - mean * scale;
}

// ---------------------------------------------------------------------------
// GEMM1 (MFMA bf16): out[65536][128] = relu(BN0(y0)) @ W1^T + b1 (pre-BN f32).
// Block tile 128x128 (grid 512), BN0+ReLU applied in fp32 during A staging.
// ---------------------------------------------------------------------------
__global__ __launch_bounds__(256) void k_gemm1(const unsigned short* __restrict__ y0,
                                               const unsigned short* __restrict__ Wb,
                                               const float* __restrict__ bias,
                                               const float* __restrict__ sc,
                                               const float* __restrict__ sh,
                                               float* __restrict__ y1) {
    __shared__ __align__(16) unsigned short As[128 * 64];
    __shared__ __align__(16) unsigned short Bs[128 * 64];
    const int t = threadIdx.x;
    const int r0 = blockIdx.x * 128;
    const int lane = t & 63;
    const int wm = (t >> 6) & 1;
    const int wn = (t >> 6) >> 1;
    const int row_s = t >> 1;
    const int slot4 = (t & 1) * 4;
    const int sw = row_s & 7;

    const unsigned short* aptr = y0 + (size_t)(r0 + row_s) * O0;
    const unsigned short* bptr = Wb + (size_t)row_s * O0;   // N=128 rows only
    unsigned short* asw = &As[row_s * 64];
    unsigned short* bsw = &Bs[row_s * 64];

    f32x4 zero = {0.f, 0.f, 0.f, 0.f};
    f32x4 acc[4][4];
#pragma unroll
    for (int i = 0; i < 4; ++i)
#pragma unroll
        for (int j = 0; j < 4; ++j) acc[i][j] = zero;

    for (int kt = 0; kt < O0; kt += 64) {
#pragma unroll
        for (int i = 0; i < 4; ++i) {
            const int slot = slot4 + i;
            const int ssw = slot ^ sw;
            const int c0 = kt + slot * 8;
            uint4 av = *(const uint4*)(aptr + c0);
            const float4 s0 = *(const float4*)&sc[c0];
            const float4 s1 = *(const float4*)&sc[c0 + 4];
            const float4 h0 = *(const float4*)&sh[c0];
            const float4 h1 = *(const float4*)&sh[c0 + 4];
            uint4 ov;
            {
                float e0 = b2f(av.x & 0xffff), e1 = b2f(av.x >> 16);
                ov.x = pack2(fmaxf(fmaf(e0, s0.x, h0.x), 0.f),
                             fmaxf(fmaf(e1, s0.y, h0.y), 0.f));
                float e2 = b2f(av.y & 0xffff), e3 = b2f(av.y >> 16);
                ov.y = pack2(fmaxf(fmaf(e2, s0.z, h0.z), 0.f),
                             fmaxf(fmaf(e3, s0.w, h0.w), 0.f));
                float e4 = b2f(av.z & 0xffff), e5 = b2f(av.z >> 16);
                ov.z = pack2(fmaxf(fmaf(e4, s1.x, h1.x), 0.f),
                             fmaxf(fmaf(e5, s1.y, h1.y), 0.f));
                float e6 = b2f(av.w & 0xffff), e7 = b2f(av.w >> 16);
                ov.w = pack2(fmaxf(fmaf(e6, s1.z, h1.z), 0.f),
                             fmaxf(fmaf(e7, s1.w, h1.w), 0.f));
            }
            *(uint4*)(asw + ssw * 8) = ov;
            if (row_s < 128) {  // always true; N=128 rows staged same way
                uint4 bv = *(const uint4*)(bptr + c0);
                *(uint4*)(bsw + ssw * 8) = bv;
            }
        }
        __syncthreads();
#pragma unroll
        for (int ks = 0; ks < 2; ++ks) {
            bf16x8 af[4], bfr[4];
#pragma unroll
            for (int fr = 0; fr < 4; ++fr) {
                const int row = wm * 64 + fr * 16 + (lane & 15);
                const int slot = (ks * 4 + (lane >> 4)) ^ (row & 7);
                af[fr] = *(const bf16x8*)&As[row * 64 + slot * 8];
            }
#pragma unroll
            for (int fc = 0; fc < 4; ++fc) {
                const int row = wn * 64 + fc * 16 + (lane & 15);
                const int slot = (ks * 4 + (lane >> 4)) ^ (row & 7);
                bfr[fc] = *(const bf16x8*)&Bs[row * 64 + slot * 8];
            }
#pragma unroll
            for (int fr = 0; fr < 4; ++fr)
#pragma unroll
                for (int fc = 0; fc < 4; ++fc)
                    acc[fr][fc] = __builtin_amdgcn_mfma_f32_16x16x32_bf16(
                        af[fr], bfr[fc], acc[fr][fc], 0, 0, 0);
        }
        __syncthreads();
    }

#pragma unroll
    for (int fc = 0; fc < 4; ++fc) {
        const int n = wn * 64 + fc * 16 + (lane & 15);
        const float bv = bias[n];
#pragma unroll
        for (int fr = 0; fr < 4; ++fr) {
#pragma unroll
            for (int j = 0; j < 4; ++j) {
                const int m = r0 + wm * 64 + fr * 16 + (lane >> 4) * 4 + j;
                y1[(size_t)m * O1 + n] = acc[fr][fc][j] + bv;
            }
        }
    }
}

__global__ __launch_bounds__(128) void k_stats1(const float* __restrict__ y,
                                                float* __restrict__ ps,
                                                float* __restrict__ pq) {
    const int t = threadIdx.x;
    const int r0 = blockIdx.x * 256;
    float s = 0.0f, q = 0.0f;
    for (int r = 0; r < 256; ++r) {
        float v = y[(size_t)(r0 + r) * O1 + t];
        s += v;
        q = fmaf(v, v, q);
    }
    ps[blockIdx.x * O1 + t] = s;
    pq[blockIdx.x * O1 + t] = q;
}

__global__ __launch_bounds__(128) void k_fin1(const float* __restrict__ ps,
                                              const float* __restrict__ pq,
                                              const float* __restrict__ gamma,
                                              const float* __restrict__ beta,
                                              float* __restrict__ sc,
                                              float* __restrict__ sh) {
    const int c = threadIdx.x;
    float s = 0.0f, q = 0.0f;
    for (int b = 0; b < 256; ++b) { s += ps[b * O1 + c]; q += pq[b * O1 + c]; }
    const float mean = s * (1.0f / NROWS);
    const float var = q * (1.0f / NROWS) - mean * mean;
    const float rs = rsqrtf(var + 1e-5f);
    const float scale = gamma[c] * rs;
    sc[c] = scale;
    sh[c] = beta[c] - mean * scale;
}

__global__ __launch_bounds__(256) void k_bnrelu(float* __restrict__ y,
                                                const float* __restrict__ sc,
                                                const float* __restrict__ sh) {
    const int e4 = blockIdx.x * 256 + threadIdx.x;
    const int c = (e4 & 31) << 2;
    float4 v = *(float4*)&y[(size_t)e4 * 4];
    const float4 s4 = *(const float4*)&sc[c];
    const float4 h4 = *(const float4*)&sh[c];
    v.x = fmaxf(fmaf(v.x, s4.x, h4.x), 0.0f);
    v.y = fmaxf(fmaf(v.y, s4.y, h4.y), 0.0f);
    v.z = fmaxf(fmaf(v.z, s4.z, h4.z), 0.0f);
    v.w = fmaxf(fmaf(v.w, s4.w, h4.w), 0.0f);
    *(float4*)&y[(size_t)e4 * 4] = v;
}

// ---------------------------------------------------------------------------
extern "C" void kernel_launch(void* const* d_in, const int* in_sizes, int n_in,
                              void* d_out, int out_size, void* d_ws, size_t ws_size,
                              hipStream_t stream) {
    const float* xyz1    = (const float*)d_in[0];
    const float* xyz2    = (const float*)d_in[1];
    const float* points1 = (const float*)d_in[2];
    const float* points2 = (const float*)d_in[3];
    const float* W0      = (const float*)d_in[4];
    const float* b0      = (const float*)d_in[5];
    const float* gamma0  = (const float*)d_in[6];
    const float* beta0   = (const float*)d_in[7];
    const float* W1      = (const float*)d_in[8];
    const float* b1      = (const float*)d_in[9];
    const float* gamma1  = (const float*)d_in[10];
    const float* beta1   = (const float*)d_in[11];
    float* out = (float*)d_out;

    char* ws = (char*)d_ws;
    unsigned short* x   = (unsigned short*)(ws + 0);            // 50,331,648 B
    unsigned short* y0  = (unsigned short*)(ws + 50331648ull);  // 33,554,432 B
    int*            idxb= (int*)           (ws + 83886080ull);  //    786,432 B
    float*          wb  = (float*)         (ws + 84672512ull);  //    786,432 B
    unsigned short* Wb0 = (unsigned short*)(ws + 85458944ull);  //    196,608 B
    unsigned short* Wb1 = (unsigned short*)(ws + 85655552ull);  //     65,536 B
    float*          ps0 = (float*)         (ws + 85721088ull);  //    262,144 B
    float*          pq0 = (float*)         (ws + 85983232ull);  //    262,144 B
    float*          ps1 = (float*)         (ws + 86245376ull);  //    131,072 B
    float*          pq1 = (float*)         (ws + 86376448ull);  //    131,072 B
    float*          sc0 = (float*)         (ws + 86507520ull);
    float*          sh0 = (float*)         (ws + 86508544ull);
    float*          sc1 = (float*)         (ws + 86509568ull);
    float*          sh1 = (float*)         (ws + 86510080ull);

    hipLaunchKernelGGL(k_cvt, dim3(512), dim3(256), 0, stream, W0, W1, Wb0, Wb1);
    hipLaunchKernelGGL(k_knn, dim3(1024), dim3(256), 0, stream, xyz1, xyz2, idxb, wb);
    hipLaunchKernelGGL(k_interp, dim3(NROWS / 8), dim3(384), 0, stream,
                       points1, points2, idxb, wb, x);
    hipLaunchKernelGGL(k_gemm0, dim3(NROWS / 128, 2), dim3(256), 0, stream,
                       x, Wb0, b0, y0);
    hipLaunchKernelGGL(k_stats0, dim3(256), dim3(256), 0, stream, y0, ps0, pq0);
    hipLaunchKernelGGL(k_fin0, dim3(1), dim3(256), 0, stream,
                       ps0, pq0, gamma0, beta0, sc0, sh0);
    hipLaunchKernelGGL(k_gemm1, dim3(NROWS / 128), dim3(256), 0, stream,
                       y0, Wb1, b1, sc0, sh0, out);
    hipLaunchKernelGGL(k_stats1, dim3(256), dim3(128), 0, stream, out, ps1, pq1);
    hipLaunchKernelGGL(k_fin1, dim3(1), dim3(128), 0, stream,
                       ps1, pq1, gamma1, beta1, sc1, sh1);
    hipLaunchKernelGGL(k_bnrelu, dim3(NROWS * O1 / 4 / 256), dim3(256), 0, stream,
                       out, sc1, sh1);
}

// Round 4
// 206.173 us; speedup vs baseline: 2.3231x; 1.0283x over previous
//
#include <hip/hip_runtime.h>
#include <cstdint>
#include <cstddef>

#define BATCH 8
#define NPTS  8192
#define MPTS  2048
#define C1    128
#define C2    256
#define K0    384   // C1 + C2
#define O0    256
#define O1    128
#define NROWS (BATCH * NPTS)  // 65536

typedef __attribute__((ext_vector_type(8))) short bf16x8;
typedef __attribute__((ext_vector_type(4))) float f32x4;

__device__ __forceinline__ unsigned short f2b(float f) {
    union { float f; unsigned int u; } v; v.f = f;
    unsigned int u = v.u + 0x7FFFu + ((v.u >> 16) & 1u);  // RNE
    return (unsigned short)(u >> 16);
}
__device__ __forceinline__ float b2f(unsigned short h) {
    union { unsigned int u; float f; } v; v.u = ((unsigned int)h) << 16; return v.f;
}
__device__ __forceinline__ unsigned int pack2(float a, float b) {
    return (unsigned int)f2b(a) | ((unsigned int)f2b(b) << 16);
}
__device__ __forceinline__ float med3(float a, float b, float c) {
    return __builtin_amdgcn_fmed3f(a, b, c);
}

// ---------------------------------------------------------------------------
// Kernel 1: brute-force 3-NN + inverse-distance weights.
// Block = 256 thr: 64 query-PAIRS x 4 segments; 128 queries/block, 512 blocks.
// s2p padded [4][513] so the 4 segments' ds_read_b128 hit disjoint 4-bank
// groups (conflict-free; was 4-way). Insertion via value-exact min/med3 +
// cndmask (identical results to if-chain, same visit order -> selection
// matches stable top_k exactly). Distance arithmetic replicates reference.
// ---------------------------------------------------------------------------
__global__ __launch_bounds__(256) void k_knn(const float* __restrict__ xyz1,
                                             const float* __restrict__ xyz2,
                                             int* __restrict__ idxo,
                                             float* __restrict__ wo) {
    __shared__ float4 s2p[4][513];   // 32,832 B (padded rows)
    __shared__ float cd[128][13];    // 6,656 B
    __shared__ int   ci[128][13];    // 6,656 B

    const int b = blockIdx.x >> 6;              // 64 blocks per batch
    const int qbase = (blockIdx.x & 63) * 128;

    for (int p = threadIdx.x; p < MPTS; p += 256) {
        const size_t src = ((size_t)b * MPTS + p) * 3;
        float px = xyz2[src + 0], py = xyz2[src + 1], pz = xyz2[src + 2];
        float sy = __fadd_rn(__fadd_rn(__fmul_rn(px, px), __fmul_rn(py, py)),
                             __fmul_rn(pz, pz));
        s2p[p >> 9][p & 511] = make_float4(px, py, pz, sy);
    }
    __syncthreads();

    const int qp  = threadIdx.x >> 2;   // 0..63 query pair
    const int seg = threadIdx.x & 3;    // 0..3
    const int nA = qbase + qp * 2;
    const int nB = nA + 1;
    const size_t qoffA = ((size_t)b * NPTS + nA) * 3;
    const float ax = xyz1[qoffA + 0], ay = xyz1[qoffA + 1], az = xyz1[qoffA + 2];
    const float bx = xyz1[qoffA + 3], by = xyz1[qoffA + 4], bz = xyz1[qoffA + 5];
    const float sA = __fadd_rn(__fadd_rn(__fmul_rn(ax, ax), __fmul_rn(ay, ay)),
                               __fmul_rn(az, az));
    const float sB = __fadd_rn(__fadd_rn(__fmul_rn(bx, bx), __fmul_rn(by, by)),
                               __fmul_rn(bz, bz));

    float a0 = 3.0e38f, a1 = 3.0e38f, a2 = 3.0e38f;
    float e0 = 3.0e38f, e1 = 3.0e38f, e2 = 3.0e38f;
    int ai0 = 0, ai1 = 0, ai2 = 0;
    int bi0 = 0, bi1 = 0, bi2 = 0;
    const int m0 = seg * 512;
    const float4* segp = &s2p[seg][0];
#pragma unroll 8
    for (int mm = 0; mm < 512; ++mm) {
        const float4 pp = segp[mm];
        const int m = m0 + mm;
        // query A
        float dotA = __fadd_rn(__fadd_rn(__fmul_rn(ax, pp.x), __fmul_rn(ay, pp.y)),
                               __fmul_rn(az, pp.z));
        float dA = __fadd_rn(__fadd_rn(__fmul_rn(-2.0f, dotA), sA), pp.w);
        // query B
        float dotB = __fadd_rn(__fadd_rn(__fmul_rn(bx, pp.x), __fmul_rn(by, pp.y)),
                               __fmul_rn(bz, pp.z));
        float dB = __fadd_rn(__fadd_rn(__fmul_rn(-2.0f, dotB), sB), pp.w);
        // insert A (indices use OLD keys, then keys update via min/med3)
        {
            const bool c0 = dA < a0, c1 = dA < a1, c2 = dA < a2;
            ai2 = c2 ? (c1 ? ai1 : m) : ai2;
            ai1 = c1 ? (c0 ? ai0 : m) : ai1;
            ai0 = c0 ? m : ai0;
            float n2 = med3(dA, a1, a2), n1 = med3(dA, a0, a1), n0 = fminf(dA, a0);
            a2 = n2; a1 = n1; a0 = n0;
        }
        // insert B
        {
            const bool c0 = dB < e0, c1 = dB < e1, c2 = dB < e2;
            bi2 = c2 ? (c1 ? bi1 : m) : bi2;
            bi1 = c1 ? (c0 ? bi0 : m) : bi1;
            bi0 = c0 ? m : bi0;
            float n2 = med3(dB, e1, e2), n1 = med3(dB, e0, e1), n0 = fminf(dB, e0);
            e2 = n2; e1 = n1; e0 = n0;
        }
    }
    const int qA = qp * 2, qB = qA + 1;
    cd[qA][seg * 3 + 0] = a0; ci[qA][seg * 3 + 0] = ai0;
    cd[qA][seg * 3 + 1] = a1; ci[qA][seg * 3 + 1] = ai1;
    cd[qA][seg * 3 + 2] = a2; ci[qA][seg * 3 + 2] = ai2;
    cd[qB][seg * 3 + 0] = e0; ci[qB][seg * 3 + 0] = bi0;
    cd[qB][seg * 3 + 1] = e1; ci[qB][seg * 3 + 1] = bi1;
    cd[qB][seg * 3 + 2] = e2; ci[qB][seg * 3 + 2] = bi2;
    __syncthreads();

    if (threadIdx.x < 128) {
        const int qq = threadIdx.x;
        float D0 = 3.0e38f, D1 = 3.0e38f, D2 = 3.0e38f;
        int I0 = 0, I1 = 0, I2 = 0;
#pragma unroll
        for (int j = 0; j < 12; ++j) {
            const float d = cd[qq][j];
            const int   i = ci[qq][j];
            const bool c0 = d < D0, c1 = d < D1, c2 = d < D2;
            I2 = c2 ? (c1 ? I1 : i) : I2;
            I1 = c1 ? (c0 ? I0 : i) : I1;
            I0 = c0 ? i : I0;
            float n2 = med3(d, D1, D2), n1 = med3(d, D0, D1), n0 = fminf(d, D0);
            D2 = n2; D1 = n1; D0 = n0;
        }
        const float r0 = 1.0f / __fadd_rn(D0, 1e-8f);
        const float r1 = 1.0f / __fadd_rn(D1, 1e-8f);
        const float r2 = 1.0f / __fadd_rn(D2, 1e-8f);
        const float norm = __fadd_rn(__fadd_rn(r0, r1), r2);

        const size_t row = (size_t)b * NPTS + qbase + qq;
        idxo[row * 3 + 0] = I0; idxo[row * 3 + 1] = I1; idxo[row * 3 + 2] = I2;
        wo[row * 3 + 0] = r0 / norm;
        wo[row * 3 + 1] = r1 / norm;
        wo[row * 3 + 2] = r2 / norm;
    }
}

// ---------------------------------------------------------------------------
// Kernel 2: gather + interpolate + concat -> x[65536][384] (bf16)
// ---------------------------------------------------------------------------
__global__ __launch_bounds__(384) void k_interp(const float* __restrict__ p1,
                                                const float* __restrict__ p2,
                                                const int* __restrict__ idx,
                                                const float* __restrict__ w,
                                                unsigned short* __restrict__ x) {
    const int t = threadIdx.x;
    const int row0 = blockIdx.x * 8;
#pragma unroll
    for (int r = 0; r < 8; ++r) {
        const int row = row0 + r;
        const int b = row >> 13;
        const int i0 = idx[row * 3 + 0];
        const int i1 = idx[row * 3 + 1];
        const int i2 = idx[row * 3 + 2];
        const float w0 = w[row * 3 + 0];
        const float w1 = w[row * 3 + 1];
        const float w2 = w[row * 3 + 2];
        float v;
        if (t < C1) {
            v = p1[(size_t)row * C1 + t];
        } else {
            const int cc = t - C1;
            const size_t base = (size_t)b * MPTS * C2;
            v = w0 * p2[base + (size_t)i0 * C2 + cc]
              + w1 * p2[base + (size_t)i1 * C2 + cc]
              + w2 * p2[base + (size_t)i2 * C2 + cc];
        }
        x[(size_t)row * K0 + t] = f2b(v);
    }
}

// ---------------------------------------------------------------------------
// Weight conversion fp32 -> bf16 ([O][K] row-major = B^T layout MFMA wants).
// ---------------------------------------------------------------------------
__global__ __launch_bounds__(256) void k_cvt(const float* __restrict__ W0,
                                             const float* __restrict__ W1,
                                             unsigned short* __restrict__ Wb0,
                                             unsigned short* __restrict__ Wb1) {
    const int e = blockIdx.x * 256 + threadIdx.x;
    if (e < O0 * K0) Wb0[e] = f2b(W0[e]);
    const int e2 = e - O0 * K0;
    if (e2 >= 0 && e2 < O1 * O0) Wb1[e2] = f2b(W1[e2]);
}

// ---------------------------------------------------------------------------
// GEMM0 (MFMA bf16) + fused column-stats partials.
// Block tile 128x128 (grid 512 x 2), 4 waves (2x2), wave 64x64, BK=64.
// XOR-swizzled LDS (write+read). Epilogue: per-block column sum/sumsq of the
// stored bf16 values -> ps/pq[(by*512+bx)*128 + col].
// ---------------------------------------------------------------------------
__global__ __launch_bounds__(256) void k_gemm0(const unsigned short* __restrict__ x,
                                               const unsigned short* __restrict__ Wb,
                                               const float* __restrict__ bias,
                                               unsigned short* __restrict__ y,
                                               float* __restrict__ ps,
                                               float* __restrict__ pq) {
    __shared__ __align__(16) unsigned short As[128 * 64];
    __shared__ __align__(16) unsigned short Bs[128 * 64];
    __shared__ float cps[2][128][2];
    const int t = threadIdx.x;
    const int r0 = blockIdx.x * 128;
    const int n0 = blockIdx.y * 128;
    const int lane = t & 63;
    const int wm = (t >> 6) & 1;
    const int wn = (t >> 6) >> 1;
    const int row_s = t >> 1;
    const int slot4 = (t & 1) * 4;
    const int sw = row_s & 7;

    const unsigned short* aptr = x  + (size_t)(r0 + row_s) * K0;
    const unsigned short* bptr = Wb + (size_t)(n0 + row_s) * K0;
    unsigned short* asw = &As[row_s * 64];
    unsigned short* bsw = &Bs[row_s * 64];

    f32x4 zero = {0.f, 0.f, 0.f, 0.f};
    f32x4 acc[4][4];
#pragma unroll
    for (int i = 0; i < 4; ++i)
#pragma unroll
        for (int j = 0; j < 4; ++j) acc[i][j] = zero;

    for (int kt = 0; kt < K0; kt += 64) {
#pragma unroll
        for (int i = 0; i < 4; ++i) {
            const int slot = slot4 + i;
            const int ssw = slot ^ sw;
            uint4 av = *(const uint4*)(aptr + kt + slot * 8);
            uint4 bv = *(const uint4*)(bptr + kt + slot * 8);
            *(uint4*)(asw + ssw * 8) = av;
            *(uint4*)(bsw + ssw * 8) = bv;
        }
        __syncthreads();
#pragma unroll
        for (int ks = 0; ks < 2; ++ks) {
            bf16x8 af[4], bfr[4];
#pragma unroll
            for (int fr = 0; fr < 4; ++fr) {
                const int row = wm * 64 + fr * 16 + (lane & 15);
                const int slot = (ks * 4 + (lane >> 4)) ^ (row & 7);
                af[fr] = *(const bf16x8*)&As[row * 64 + slot * 8];
            }
#pragma unroll
            for (int fc = 0; fc < 4; ++fc) {
                const int row = wn * 64 + fc * 16 + (lane & 15);
                const int slot = (ks * 4 + (lane >> 4)) ^ (row & 7);
                bfr[fc] = *(const bf16x8*)&Bs[row * 64 + slot * 8];
            }
#pragma unroll
            for (int fr = 0; fr < 4; ++fr)
#pragma unroll
                for (int fc = 0; fc < 4; ++fc)
                    acc[fr][fc] = __builtin_amdgcn_mfma_f32_16x16x32_bf16(
                        af[fr], bfr[fc], acc[fr][fc], 0, 0, 0);
        }
        __syncthreads();
    }

#pragma unroll
    for (int fc = 0; fc < 4; ++fc) {
        const int cl = wn * 64 + fc * 16 + (lane & 15);
        const int n = n0 + cl;
        const float bv = bias[n];
        float s = 0.0f, q = 0.0f;
#pragma unroll
        for (int fr = 0; fr < 4; ++fr) {
#pragma unroll
            for (int j = 0; j < 4; ++j) {
                const int m = r0 + wm * 64 + fr * 16 + (lane >> 4) * 4 + j;
                const unsigned short st = f2b(acc[fr][fc][j] + bv);
                y[(size_t)m * O0 + n] = st;
                const float v = b2f(st);
                s += v;
                q = fmaf(v, v, q);
            }
        }
        s += __shfl_xor(s, 16); s += __shfl_xor(s, 32);
        q += __shfl_xor(q, 16); q += __shfl_xor(q, 32);
        if ((lane >> 4) == 0) { cps[wm][cl][0] = s; cps[wm][cl][1] = q; }
    }
    __syncthreads();
    if (t < 128) {
        const float s = cps[0][t][0] + cps[1][t][0];
        const float q = cps[0][t][1] + cps[1][t][1];
        const size_t o = ((size_t)blockIdx.y * 512 + blockIdx.x) * 128 + t;
        ps[o] = s; pq[o] = q;
    }
}

__global__ __launch_bounds__(256) void k_fin0(const float* __restrict__ ps,
                                              const float* __restrict__ pq,
                                              const float* __restrict__ gamma,
                                              const float* __restrict__ beta,
                                              float* __restrict__ sc,
                                              float* __restrict__ sh) {
    const int c = threadIdx.x;
    const int by = c >> 7, cl = c & 127;
    float s = 0.0f, q = 0.0f;
    for (int bx = 0; bx < 512; ++bx) {
        const size_t o = ((size_t)by * 512 + bx) * 128 + cl;
        s += ps[o]; q += pq[o];
    }
    const float mean = s * (1.0f / NROWS);
    const float var = q * (1.0f / NROWS) - mean * mean;
    const float rs = rsqrtf(var + 1e-5f);
    const float scale = gamma[c] * rs;
    sc[c] = scale;
    sh[c] = beta[c] - mean * scale;
}

// ---------------------------------------------------------------------------
// GEMM1 (MFMA bf16) + fused column-stats partials; BN0+ReLU on A-load.
// ---------------------------------------------------------------------------
__global__ __launch_bounds__(256) void k_gemm1(const unsigned short* __restrict__ y0,
                                               const unsigned short* __restrict__ Wb,
                                               const float* __restrict__ bias,
                                               const float* __restrict__ sc,
                                               const float* __restrict__ sh,
                                               float* __restrict__ y1,
                                               float* __restrict__ ps,
                                               float* __restrict__ pq) {
    __shared__ __align__(16) unsigned short As[128 * 64];
    __shared__ __align__(16) unsigned short Bs[128 * 64];
    __shared__ float cps[2][128][2];
    const int t = threadIdx.x;
    const int r0 = blockIdx.x * 128;
    const int lane = t & 63;
    const int wm = (t >> 6) & 1;
    const int wn = (t >> 6) >> 1;
    const int row_s = t >> 1;
    const int slot4 = (t & 1) * 4;
    const int sw = row_s & 7;

    const unsigned short* aptr = y0 + (size_t)(r0 + row_s) * O0;
    const unsigned short* bptr = Wb + (size_t)row_s * O0;
    unsigned short* asw = &As[row_s * 64];
    unsigned short* bsw = &Bs[row_s * 64];

    f32x4 zero = {0.f, 0.f, 0.f, 0.f};
    f32x4 acc[4][4];
#pragma unroll
    for (int i = 0; i < 4; ++i)
#pragma unroll
        for (int j = 0; j < 4; ++j) acc[i][j] = zero;

    for (int kt = 0; kt < O0; kt += 64) {
#pragma unroll
        for (int i = 0; i < 4; ++i) {
            const int slot = slot4 + i;
            const int ssw = slot ^ sw;
            const int c0 = kt + slot * 8;
            uint4 av = *(const uint4*)(aptr + c0);
            const float4 s0 = *(const float4*)&sc[c0];
            const float4 s1 = *(const float4*)&sc[c0 + 4];
            const float4 h0 = *(const float4*)&sh[c0];
            const float4 h1 = *(const float4*)&sh[c0 + 4];
            uint4 ov;
            {
                float v0 = b2f(av.x & 0xffff), v1 = b2f(av.x >> 16);
                ov.x = pack2(fmaxf(fmaf(v0, s0.x, h0.x), 0.f),
                             fmaxf(fmaf(v1, s0.y, h0.y), 0.f));
                float v2 = b2f(av.y & 0xffff), v3 = b2f(av.y >> 16);
                ov.y = pack2(fmaxf(fmaf(v2, s0.z, h0.z), 0.f),
                             fmaxf(fmaf(v3, s0.w, h0.w), 0.f));
                float v4 = b2f(av.z & 0xffff), v5 = b2f(av.z >> 16);
                ov.z = pack2(fmaxf(fmaf(v4, s1.x, h1.x), 0.f),
                             fmaxf(fmaf(v5, s1.y, h1.y), 0.f));
                float v6 = b2f(av.w & 0xffff), v7 = b2f(av.w >> 16);
                ov.w = pack2(fmaxf(fmaf(v6, s1.z, h1.z), 0.f),
                             fmaxf(fmaf(v7, s1.w, h1.w), 0.f));
            }
            *(uint4*)(asw + ssw * 8) = ov;
            uint4 bv = *(const uint4*)(bptr + c0);
            *(uint4*)(bsw + ssw * 8) = bv;
        }
        __syncthreads();
#pragma unroll
        for (int ks = 0; ks < 2; ++ks) {
            bf16x8 af[4], bfr[4];
#pragma unroll
            for (int fr = 0; fr < 4; ++fr) {
                const int row = wm * 64 + fr * 16 + (lane & 15);
                const int slot = (ks * 4 + (lane >> 4)) ^ (row & 7);
                af[fr] = *(const bf16x8*)&As[row * 64 + slot * 8];
            }
#pragma unroll
            for (int fc = 0; fc < 4; ++fc) {
                const int row = wn * 64 + fc * 16 + (lane & 15);
                const int slot = (ks * 4 + (lane >> 4)) ^ (row & 7);
                bfr[fc] = *(const bf16x8*)&Bs[row * 64 + slot * 8];
            }
#pragma unroll
            for (int fr = 0; fr < 4; ++fr)
#pragma unroll
                for (int fc = 0; fc < 4; ++fc)
                    acc[fr][fc] = __builtin_amdgcn_mfma_f32_16x16x32_bf16(
                        af[fr], bfr[fc], acc[fr][fc], 0, 0, 0);
        }
        __syncthreads();
    }

#pragma unroll
    for (int fc = 0; fc < 4; ++fc) {
        const int cl = wn * 64 + fc * 16 + (lane & 15);
        const float bv = bias[cl];
        float s = 0.0f, q = 0.0f;
#pragma unroll
        for (int fr = 0; fr < 4; ++fr) {
#pragma unroll
            for (int j = 0; j < 4; ++j) {
                const int m = r0 + wm * 64 + fr * 16 + (lane >> 4) * 4 + j;
                const float v = acc[fr][fc][j] + bv;
                y1[(size_t)m * O1 + cl] = v;
                s += v;
                q = fmaf(v, v, q);
            }
        }
        s += __shfl_xor(s, 16); s += __shfl_xor(s, 32);
        q += __shfl_xor(q, 16); q += __shfl_xor(q, 32);
        if ((lane >> 4) == 0) { cps[wm][cl][0] = s; cps[wm][cl][1] = q; }
    }
    __syncthreads();
    if (t < 128) {
        const float s = cps[0][t][0] + cps[1][t][0];
        const float q = cps[0][t][1] + cps[1][t][1];
        const size_t o = (size_t)blockIdx.x * 128 + t;
        ps[o] = s; pq[o] = q;
    }
}

__global__ __launch_bounds__(128) void k_fin1(const float* __restrict__ ps,
                                              const float* __restrict__ pq,
                                              const float* __restrict__ gamma,
                                              const float* __restrict__ beta,
                                              float* __restrict__ sc,
                                              float* __restrict__ sh) {
    const int c = threadIdx.x;
    float s = 0.0f, q = 0.0f;
    for (int bx = 0; bx < 512; ++bx) {
        const size_t o = (size_t)bx * 128 + c;
        s += ps[o]; q += pq[o];
    }
    const float mean = s * (1.0f / NROWS);
    const float var = q * (1.0f / NROWS) - mean * mean;
    const float rs = rsqrtf(var + 1e-5f);
    const float scale = gamma[c] * rs;
    sc[c] = scale;
    sh[c] = beta[c] - mean * scale;
}

__global__ __launch_bounds__(256) void k_bnrelu(float* __restrict__ y,
                                                const float* __restrict__ sc,
                                                const float* __restrict__ sh) {
    const int e4 = blockIdx.x * 256 + threadIdx.x;
    const int c = (e4 & 31) << 2;
    float4 v = *(float4*)&y[(size_t)e4 * 4];
    const float4 s4 = *(const float4*)&sc[c];
    const float4 h4 = *(const float4*)&sh[c];
    v.x = fmaxf(fmaf(v.x, s4.x, h4.x), 0.0f);
    v.y = fmaxf(fmaf(v.y, s4.y, h4.y), 0.0f);
    v.z = fmaxf(fmaf(v.z, s4.z, h4.z), 0.0f);
    v.w = fmaxf(fmaf(v.w, s4.w, h4.w), 0.0f);
    *(float4*)&y[(size_t)e4 * 4] = v;
}

// ---------------------------------------------------------------------------
extern "C" void kernel_launch(void* const* d_in, const int* in_sizes, int n_in,
                              void* d_out, int out_size, void* d_ws, size_t ws_size,
                              hipStream_t stream) {
    const float* xyz1    = (const float*)d_in[0];
    const float* xyz2    = (const float*)d_in[1];
    const float* points1 = (const float*)d_in[2];
    const float* points2 = (const float*)d_in[3];
    const float* W0      = (const float*)d_in[4];
    const float* b0      = (const float*)d_in[5];
    const float* gamma0  = (const float*)d_in[6];
    const float* beta0   = (const float*)d_in[7];
    const float* W1      = (const float*)d_in[8];
    const float* b1      = (const float*)d_in[9];
    const float* gamma1  = (const float*)d_in[10];
    const float* beta1   = (const float*)d_in[11];
    float* out = (float*)d_out;

    char* ws = (char*)d_ws;
    unsigned short* x   = (unsigned short*)(ws + 0);            // 50,331,648 B
    unsigned short* y0  = (unsigned short*)(ws + 50331648ull);  // 33,554,432 B
    int*            idxb= (int*)           (ws + 83886080ull);  //    786,432 B
    float*          wb  = (float*)         (ws + 84672512ull);  //    786,432 B
    unsigned short* Wb0 = (unsigned short*)(ws + 85458944ull);  //    196,608 B
    unsigned short* Wb1 = (unsigned short*)(ws + 85655552ull);  //     65,536 B
    float*          ps0 = (float*)         (ws + 85721088ull);  //    524,288 B
    float*          pq0 = (float*)         (ws + 86245376ull);  //    524,288 B
    float*          ps1 = (float*)         (ws + 86769664ull);  //    262,144 B
    float*          pq1 = (float*)         (ws + 87031808ull);  //    262,144 B
    float*          sc0 = (float*)         (ws + 87293952ull);
    float*          sh0 = (float*)         (ws + 87295232ull);
    float*          sc1 = (float*)         (ws + 87296512ull);
    float*          sh1 = (float*)         (ws + 87297792ull);

    hipLaunchKernelGGL(k_cvt, dim3(512), dim3(256), 0, stream, W0, W1, Wb0, Wb1);
    hipLaunchKernelGGL(k_knn, dim3(512), dim3(256), 0, stream, xyz1, xyz2, idxb, wb);
    hipLaunchKernelGGL(k_interp, dim3(NROWS / 8), dim3(384), 0, stream,
                       points1, points2, idxb, wb, x);
    hipLaunchKernelGGL(k_gemm0, dim3(NROWS / 128, 2), dim3(256), 0, stream,
                       x, Wb0, b0, y0, ps0, pq0);
    hipLaunchKernelGGL(k_fin0, dim3(1), dim3(256), 0, stream,
                       ps0, pq0, gamma0, beta0, sc0, sh0);
    hipLaunchKernelGGL(k_gemm1, dim3(NROWS / 128), dim3(256), 0, stream,
                       y0, Wb1, b1, sc0, sh0, out, ps1, pq1);
    hipLaunchKernelGGL(k_fin1, dim3(1), dim3(128), 0, stream,
                       ps1, pq1, gamma1, beta1, sc1, sh1);
    hipLaunchKernelGGL(k_bnrelu, dim3(NROWS * O1 / 4 / 256), dim3(256), 0, stream,
                       out, sc1, sh1);
}

// Round 6
// 197.393 us; speedup vs baseline: 2.4264x; 1.0445x over previous
//
#include <hip/hip_runtime.h>
#include <cstdint>
#include <cstddef>

#define BATCH 8
#define NPTS  8192
#define MPTS  2048
#define C1    128
#define C2    256
#define K0    384   // C1 + C2
#define O0    256
#define O1    128
#define NROWS (BATCH * NPTS)  // 65536

typedef __attribute__((ext_vector_type(8))) short bf16x8;
typedef __attribute__((ext_vector_type(4))) float f32x4;

__device__ __forceinline__ unsigned short f2b(float f) {
    union { float f; unsigned int u; } v; v.f = f;
    unsigned int u = v.u + 0x7FFFu + ((v.u >> 16) & 1u);  // RNE
    return (unsigned short)(u >> 16);
}
__device__ __forceinline__ float b2f(unsigned short h) {
    union { unsigned int u; float f; } v; v.u = ((unsigned int)h) << 16; return v.f;
}
__device__ __forceinline__ unsigned int pack2(float a, float b) {
    return (unsigned int)f2b(a) | ((unsigned int)f2b(b) << 16);
}
__device__ __forceinline__ float med3(float a, float b, float c) {
    return __builtin_amdgcn_fmed3f(a, b, c);
}

// Merge two stably-sorted triples (x = lower-global-index side) into top-3.
// Strict < everywhere => on ties the x-side (earlier index) wins, replicating
// stable top_k semantics.
__device__ __forceinline__ void merge3(float x0, float x1, float x2,
                                       int ix0, int ix1, int ix2,
                                       float y0, float y1, float y2,
                                       int iy0, int iy1, int iy2,
                                       float& z0, float& z1, float& z2,
                                       int& iz0, int& iz1, int& iz2) {
    const bool c0 = y0 < x0;
    const bool c1a = y1 < x0;
    const bool c1b = y0 < x1;
    z0 = c0 ? y0 : x0;  iz0 = c0 ? iy0 : ix0;
    const float z1A = c1a ? y1 : x0; const int iz1A = c1a ? iy1 : ix0;
    const float z1B = c1b ? y0 : x1; const int iz1B = c1b ? iy0 : ix1;
    z1 = c0 ? z1A : z1B; iz1 = c0 ? iz1A : iz1B;
    const bool mA1c = y2 < x0;
    const bool mA2c = y1 < x1;
    const bool mB2c = y0 < x2;
    const float mA1 = mA1c ? y2 : x0; const int imA1 = mA1c ? iy2 : ix0;
    const float mA2 = mA2c ? y1 : x1; const int imA2 = mA2c ? iy1 : ix1;
    const float mB2 = mB2c ? y0 : x2; const int imB2 = mB2c ? iy0 : ix2;
    const float z2A = c1a ? mA1 : mA2; const int iz2A = c1a ? imA1 : imA2;
    const float z2B = c1b ? mA2 : mB2; const int iz2B = c1b ? imA2 : imB2;
    z2 = c0 ? z2A : z2B; iz2 = c0 ? iz2A : iz2B;
}

// ---------------------------------------------------------------------------
// Kernel 1: brute-force 3-NN + inverse-distance weights.
// Block = 256 thr = 32 query-pairs x 8 segments (64 queries/block, 1024 blks
// -> 4 blocks/CU). Seg stride 257 float4s spreads the 8 seg addresses over
// all 32 banks (8-way same-address broadcast within a seg -> conflict-free).
// Partial top-3s merge in-wave via shfl_xor butterfly (stable, lower-seg
// wins ties). Distance arithmetic replicates the reference exactly.
// ---------------------------------------------------------------------------
__global__ __launch_bounds__(256) void k_knn(const float* __restrict__ xyz1,
                                             const float* __restrict__ xyz2,
                                             int* __restrict__ idxo,
                                             float* __restrict__ wo) {
    __shared__ float4 s2p[8][257];   // 32,896 B

    const int b = blockIdx.x >> 7;              // 128 blocks per batch
    const int qbase = (blockIdx.x & 127) * 64;

    for (int p = threadIdx.x; p < MPTS; p += 256) {
        const size_t src = ((size_t)b * MPTS + p) * 3;
        float px = xyz2[src + 0], py = xyz2[src + 1], pz = xyz2[src + 2];
        float sy = __fadd_rn(__fadd_rn(__fmul_rn(px, px), __fmul_rn(py, py)),
                             __fmul_rn(pz, pz));
        s2p[p >> 8][p & 255] = make_float4(px, py, pz, sy);
    }
    __syncthreads();

    const int qp  = threadIdx.x >> 3;   // 0..31 query pair
    const int seg = threadIdx.x & 7;    // 0..7
    const int nA = qbase + qp * 2;
    const size_t qoffA = ((size_t)b * NPTS + nA) * 3;
    const float ax = xyz1[qoffA + 0], ay = xyz1[qoffA + 1], az = xyz1[qoffA + 2];
    const float bx = xyz1[qoffA + 3], by = xyz1[qoffA + 4], bz = xyz1[qoffA + 5];
    const float sA = __fadd_rn(__fadd_rn(__fmul_rn(ax, ax), __fmul_rn(ay, ay)),
                               __fmul_rn(az, az));
    const float sB = __fadd_rn(__fadd_rn(__fmul_rn(bx, bx), __fmul_rn(by, by)),
                               __fmul_rn(bz, bz));

    float a0 = 3.0e38f, a1 = 3.0e38f, a2 = 3.0e38f;
    float e0 = 3.0e38f, e1 = 3.0e38f, e2 = 3.0e38f;
    int ai0 = 0, ai1 = 0, ai2 = 0;
    int bi0 = 0, bi1 = 0, bi2 = 0;
    const int m0 = seg * 256;
    const float4* segp = &s2p[seg][0];
#pragma unroll 8
    for (int mm = 0; mm < 256; ++mm) {
        const float4 pp = segp[mm];
        const int m = m0 + mm;
        float dotA = __fadd_rn(__fadd_rn(__fmul_rn(ax, pp.x), __fmul_rn(ay, pp.y)),
                               __fmul_rn(az, pp.z));
        float dA = __fadd_rn(__fadd_rn(__fmul_rn(-2.0f, dotA), sA), pp.w);
        float dotB = __fadd_rn(__fadd_rn(__fmul_rn(bx, pp.x), __fmul_rn(by, pp.y)),
                               __fmul_rn(bz, pp.z));
        float dB = __fadd_rn(__fadd_rn(__fmul_rn(-2.0f, dotB), sB), pp.w);
        {
            const bool c0 = dA < a0, c1 = dA < a1, c2 = dA < a2;
            ai2 = c2 ? (c1 ? ai1 : m) : ai2;
            ai1 = c1 ? (c0 ? ai0 : m) : ai1;
            ai0 = c0 ? m : ai0;
            float n2 = med3(dA, a1, a2), n1 = med3(dA, a0, a1), n0 = fminf(dA, a0);
            a2 = n2; a1 = n1; a0 = n0;
        }
        {
            const bool c0 = dB < e0, c1 = dB < e1, c2 = dB < e2;
            bi2 = c2 ? (c1 ? bi1 : m) : bi2;
            bi1 = c1 ? (c0 ? bi0 : m) : bi1;
            bi0 = c0 ? m : bi0;
            float n2 = med3(dB, e1, e2), n1 = med3(dB, e0, e1), n0 = fminf(dB, e0);
            e2 = n2; e1 = n1; e0 = n0;
        }
    }

    // In-wave butterfly merge across the 8 seg lanes (stable, lower-seg wins).
#pragma unroll
    for (int k = 1; k <= 4; k <<= 1) {
        const bool up = (threadIdx.x & k) != 0;
        {
            float p0 = __shfl_xor(a0, k), p1 = __shfl_xor(a1, k), p2 = __shfl_xor(a2, k);
            int   q0 = __shfl_xor(ai0, k), q1 = __shfl_xor(ai1, k), q2 = __shfl_xor(ai2, k);
            float x0 = up ? p0 : a0, x1 = up ? p1 : a1, x2 = up ? p2 : a2;
            int  ix0 = up ? q0 : ai0, ix1 = up ? q1 : ai1, ix2 = up ? q2 : ai2;
            float y0 = up ? a0 : p0, y1 = up ? a1 : p1, y2 = up ? a2 : p2;
            int  iy0 = up ? ai0 : q0, iy1 = up ? ai1 : q1, iy2 = up ? ai2 : q2;
            merge3(x0, x1, x2, ix0, ix1, ix2, y0, y1, y2, iy0, iy1, iy2,
                   a0, a1, a2, ai0, ai1, ai2);
        }
        {
            float p0 = __shfl_xor(e0, k), p1 = __shfl_xor(e1, k), p2 = __shfl_xor(e2, k);
            int   q0 = __shfl_xor(bi0, k), q1 = __shfl_xor(bi1, k), q2 = __shfl_xor(bi2, k);
            float x0 = up ? p0 : e0, x1 = up ? p1 : e1, x2 = up ? p2 : e2;
            int  ix0 = up ? q0 : bi0, ix1 = up ? q1 : bi1, ix2 = up ? q2 : bi2;
            float y0 = up ? e0 : p0, y1 = up ? e1 : p1, y2 = up ? e2 : p2;
            int  iy0 = up ? bi0 : q0, iy1 = up ? bi1 : q1, iy2 = up ? bi2 : q2;
            merge3(x0, x1, x2, ix0, ix1, ix2, y0, y1, y2, iy0, iy1, iy2,
                   e0, e1, e2, bi0, bi1, bi2);
        }
    }

    if (seg == 0) {
        {
            const float r0 = 1.0f / __fadd_rn(a0, 1e-8f);
            const float r1 = 1.0f / __fadd_rn(a1, 1e-8f);
            const float r2 = 1.0f / __fadd_rn(a2, 1e-8f);
            const float norm = __fadd_rn(__fadd_rn(r0, r1), r2);
            const size_t row = (size_t)b * NPTS + nA;
            idxo[row * 3 + 0] = ai0; idxo[row * 3 + 1] = ai1; idxo[row * 3 + 2] = ai2;
            wo[row * 3 + 0] = r0 / norm;
            wo[row * 3 + 1] = r1 / norm;
            wo[row * 3 + 2] = r2 / norm;
        }
        {
            const float r0 = 1.0f / __fadd_rn(e0, 1e-8f);
            const float r1 = 1.0f / __fadd_rn(e1, 1e-8f);
            const float r2 = 1.0f / __fadd_rn(e2, 1e-8f);
            const float norm = __fadd_rn(__fadd_rn(r0, r1), r2);
            const size_t row = (size_t)b * NPTS + nA + 1;
            idxo[row * 3 + 0] = bi0; idxo[row * 3 + 1] = bi1; idxo[row * 3 + 2] = bi2;
            wo[row * 3 + 0] = r0 / norm;
            wo[row * 3 + 1] = r1 / norm;
            wo[row * 3 + 2] = r2 / norm;
        }
    }
}

// ---------------------------------------------------------------------------
// Kernel 2: gather + interpolate + concat -> x[65536][384] bf16, vectorized.
// Block 256 = 16 rows x 16 col-threads; each col-thread does 3 8-col chunks.
// ---------------------------------------------------------------------------
__global__ __launch_bounds__(256) void k_interp(const float* __restrict__ p1,
                                                const float* __restrict__ p2,
                                                const int* __restrict__ idx,
                                                const float* __restrict__ w,
                                                unsigned short* __restrict__ x) {
    const int t = threadIdx.x;
    const int r = blockIdx.x * 16 + (t >> 4);
    const int tin = t & 15;
    const int b = r >> 13;
    const int i0 = idx[r * 3 + 0];
    const int i1 = idx[r * 3 + 1];
    const int i2 = idx[r * 3 + 2];
    const float w0 = w[r * 3 + 0];
    const float w1 = w[r * 3 + 1];
    const float w2 = w[r * 3 + 2];
    const float* base = p2 + (size_t)b * MPTS * C2;
    const float* g0 = base + (size_t)i0 * C2;
    const float* g1 = base + (size_t)i1 * C2;
    const float* g2 = base + (size_t)i2 * C2;

#pragma unroll
    for (int k = 0; k < 3; ++k) {
        const int c = tin + k * 16;       // chunk 0..47
        const int col = c * 8;
        uint4 o;
        if (c < 16) {
            const float4 u = *(const float4*)&p1[(size_t)r * C1 + col];
            const float4 v = *(const float4*)&p1[(size_t)r * C1 + col + 4];
            o.x = pack2(u.x, u.y); o.y = pack2(u.z, u.w);
            o.z = pack2(v.x, v.y); o.w = pack2(v.z, v.w);
        } else {
            const int cc = col - C1;
            const float4 u0 = *(const float4*)&g0[cc];
            const float4 u1 = *(const float4*)&g0[cc + 4];
            const float4 v0 = *(const float4*)&g1[cc];
            const float4 v1 = *(const float4*)&g1[cc + 4];
            const float4 t0 = *(const float4*)&g2[cc];
            const float4 t1 = *(const float4*)&g2[cc + 4];
            const float f0 = w0 * u0.x + w1 * v0.x + w2 * t0.x;
            const float f1 = w0 * u0.y + w1 * v0.y + w2 * t0.y;
            const float f2 = w0 * u0.z + w1 * v0.z + w2 * t0.z;
            const float f3 = w0 * u0.w + w1 * v0.w + w2 * t0.w;
            const float f4 = w0 * u1.x + w1 * v1.x + w2 * t1.x;
            const float f5 = w0 * u1.y + w1 * v1.y + w2 * t1.y;
            const float f6 = w0 * u1.z + w1 * v1.z + w2 * t1.z;
            const float f7 = w0 * u1.w + w1 * v1.w + w2 * t1.w;
            o.x = pack2(f0, f1); o.y = pack2(f2, f3);
            o.z = pack2(f4, f5); o.w = pack2(f6, f7);
        }
        *(uint4*)&x[(size_t)r * K0 + col] = o;
    }
}

// ---------------------------------------------------------------------------
// Weight conversion fp32 -> bf16 ([O][K] row-major = B^T layout MFMA wants).
// ---------------------------------------------------------------------------
__global__ __launch_bounds__(256) void k_cvt(const float* __restrict__ W0,
                                             const float* __restrict__ W1,
                                             unsigned short* __restrict__ Wb0,
                                             unsigned short* __restrict__ Wb1) {
    const int e = blockIdx.x * 256 + threadIdx.x;
    if (e < O0 * K0) Wb0[e] = f2b(W0[e]);
    const int e2 = e - O0 * K0;
    if (e2 >= 0 && e2 < O1 * O0) Wb1[e2] = f2b(W1[e2]);
}

// ---------------------------------------------------------------------------
// GEMM0 (MFMA bf16) + fused column-stats partials.
// Block tile 128x256 (grid 512), 512 thr = 8 waves (2x4), wave 64x64, BK=64.
// x read once. XOR-swizzled LDS (write+read sides).
// ---------------------------------------------------------------------------
__global__ __launch_bounds__(512) void k_gemm0(const unsigned short* __restrict__ x,
                                               const unsigned short* __restrict__ Wb,
                                               const float* __restrict__ bias,
                                               unsigned short* __restrict__ y,
                                               float* __restrict__ ps,
                                               float* __restrict__ pq) {
    __shared__ __align__(16) unsigned short As[128 * 64];  // 16 KB
    __shared__ __align__(16) unsigned short Bs[256 * 64];  // 32 KB
    __shared__ float cps[2][256][2];                       //  4 KB
    const int t = threadIdx.x;
    const int r0 = blockIdx.x * 128;
    const int lane = t & 63;
    const int wid = t >> 6;
    const int wm = wid & 1;
    const int wn = wid >> 1;          // 0..3

    const int row_a = t >> 2;          // 0..127
    const int sa0 = (t & 3) * 2;       // 2 slots
    const int row_b = t >> 1;          // 0..255
    const int sb0 = (t & 1) * 4;       // 4 slots

    const unsigned short* aptr = x  + (size_t)(r0 + row_a) * K0;
    const unsigned short* bptr = Wb + (size_t)row_b * K0;
    unsigned short* asw = &As[row_a * 64];
    unsigned short* bsw = &Bs[row_b * 64];
    const int swa = row_a & 7;
    const int swb = row_b & 7;

    f32x4 zero = {0.f, 0.f, 0.f, 0.f};
    f32x4 acc[4][4];
#pragma unroll
    for (int i = 0; i < 4; ++i)
#pragma unroll
        for (int j = 0; j < 4; ++j) acc[i][j] = zero;

    for (int kt = 0; kt < K0; kt += 64) {
#pragma unroll
        for (int i = 0; i < 2; ++i) {
            const int slot = sa0 + i;
            *(uint4*)(asw + (slot ^ swa) * 8) = *(const uint4*)(aptr + kt + slot * 8);
        }
#pragma unroll
        for (int i = 0; i < 4; ++i) {
            const int slot = sb0 + i;
            *(uint4*)(bsw + (slot ^ swb) * 8) = *(const uint4*)(bptr + kt + slot * 8);
        }
        __syncthreads();
#pragma unroll
        for (int ks = 0; ks < 2; ++ks) {
            bf16x8 af[4], bfr[4];
#pragma unroll
            for (int fr = 0; fr < 4; ++fr) {
                const int row = wm * 64 + fr * 16 + (lane & 15);
                const int slot = (ks * 4 + (lane >> 4)) ^ (row & 7);
                af[fr] = *(const bf16x8*)&As[row * 64 + slot * 8];
            }
#pragma unroll
            for (int fc = 0; fc < 4; ++fc) {
                const int row = wn * 64 + fc * 16 + (lane & 15);
                const int slot = (ks * 4 + (lane >> 4)) ^ (row & 7);
                bfr[fc] = *(const bf16x8*)&Bs[row * 64 + slot * 8];
            }
#pragma unroll
            for (int fr = 0; fr < 4; ++fr)
#pragma unroll
                for (int fc = 0; fc < 4; ++fc)
                    acc[fr][fc] = __builtin_amdgcn_mfma_f32_16x16x32_bf16(
                        af[fr], bfr[fc], acc[fr][fc], 0, 0, 0);
        }
        __syncthreads();
    }

#pragma unroll
    for (int fc = 0; fc < 4; ++fc) {
        const int n = wn * 64 + fc * 16 + (lane & 15);   // 0..255
        const float bv = bias[n];
        float s = 0.0f, q = 0.0f;
#pragma unroll
        for (int fr = 0; fr < 4; ++fr) {
#pragma unroll
            for (int j = 0; j < 4; ++j) {
                const int m = r0 + wm * 64 + fr * 16 + (lane >> 4) * 4 + j;
                const unsigned short st = f2b(acc[fr][fc][j] + bv);
                y[(size_t)m * O0 + n] = st;
                const float v = b2f(st);
                s += v;
                q = fmaf(v, v, q);
            }
        }
        s += __shfl_xor(s, 16); s += __shfl_xor(s, 32);
        q += __shfl_xor(q, 16); q += __shfl_xor(q, 32);
        if ((lane >> 4) == 0) { cps[wm][n][0] = s; cps[wm][n][1] = q; }
    }
    __syncthreads();
    if (t < 256) {
        const float s = cps[0][t][0] + cps[1][t][0];
        const float q = cps[0][t][1] + cps[1][t][1];
        const size_t o = (size_t)blockIdx.x * 256 + t;
        ps[o] = s; pq[o] = q;
    }
}

// fin0: reduce 512 partials per column (1 block, 1024 thr = 4 quarters x 256).
__global__ __launch_bounds__(1024) void k_fin0(const float* __restrict__ ps,
                                               const float* __restrict__ pq,
                                               const float* __restrict__ gamma,
                                               const float* __restrict__ beta,
                                               float* __restrict__ sc,
                                               float* __restrict__ sh) {
    __shared__ float red[4][256][2];
    const int tid = threadIdx.x;
    const int c = tid & 255, qr = tid >> 8;
    float s = 0.0f, q = 0.0f;
    for (int bx = qr * 128; bx < qr * 128 + 128; ++bx) {
        s += ps[(size_t)bx * 256 + c];
        q += pq[(size_t)bx * 256 + c];
    }
    red[qr][c][0] = s; red[qr][c][1] = q;
    __syncthreads();
    if (tid < 256) {
        const float ss = ((red[0][tid][0] + red[1][tid][0]) +
                          (red[2][tid][0] + red[3][tid][0]));
        const float qq = ((red[0][tid][1] + red[1][tid][1]) +
                          (red[2][tid][1] + red[3][tid][1]));
        const float mean = ss * (1.0f / NROWS);
        const float var = qq * (1.0f / NROWS) - mean * mean;
        const float rs = rsqrtf(var + 1e-5f);
        const float scale = gamma[tid] * rs;
        sc[tid] = scale;
        sh[tid] = beta[tid] - mean * scale;
    }
}

// ---------------------------------------------------------------------------
// GEMM1 (MFMA bf16) + fused column-stats partials; BN0+ReLU on A-load.
// Block tile 128x128 (grid 512), 256 thr. Writes pre-BN y1 (fp32) to out.
// ---------------------------------------------------------------------------
__global__ __launch_bounds__(256) void k_gemm1(const unsigned short* __restrict__ y0,
                                               const unsigned short* __restrict__ Wb,
                                               const float* __restrict__ bias,
                                               const float* __restrict__ sc,
                                               const float* __restrict__ sh,
                                               float* __restrict__ y1,
                                               float* __restrict__ ps,
                                               float* __restrict__ pq) {
    __shared__ __align__(16) unsigned short As[128 * 64];
    __shared__ __align__(16) unsigned short Bs[128 * 64];
    __shared__ float cps[2][128][2];
    const int t = threadIdx.x;
    const int r0 = blockIdx.x * 128;
    const int lane = t & 63;
    const int wm = (t >> 6) & 1;
    const int wn = (t >> 6) >> 1;
    const int row_s = t >> 1;
    const int slot4 = (t & 1) * 4;
    const int sw = row_s & 7;

    const unsigned short* aptr = y0 + (size_t)(r0 + row_s) * O0;
    const unsigned short* bptr = Wb + (size_t)row_s * O0;
    unsigned short* asw = &As[row_s * 64];
    unsigned short* bsw = &Bs[row_s * 64];

    f32x4 zero = {0.f, 0.f, 0.f, 0.f};
    f32x4 acc[4][4];
#pragma unroll
    for (int i = 0; i < 4; ++i)
#pragma unroll
        for (int j = 0; j < 4; ++j) acc[i][j] = zero;

    for (int kt = 0; kt < O0; kt += 64) {
#pragma unroll
        for (int i = 0; i < 4; ++i) {
            const int slot = slot4 + i;
            const int ssw = slot ^ sw;
            const int c0 = kt + slot * 8;
            uint4 av = *(const uint4*)(aptr + c0);
            const float4 s0 = *(const float4*)&sc[c0];
            const float4 s1 = *(const float4*)&sc[c0 + 4];
            const float4 h0 = *(const float4*)&sh[c0];
            const float4 h1 = *(const float4*)&sh[c0 + 4];
            uint4 ov;
            {
                float v0 = b2f(av.x & 0xffff), v1 = b2f(av.x >> 16);
                ov.x = pack2(fmaxf(fmaf(v0, s0.x, h0.x), 0.f),
                             fmaxf(fmaf(v1, s0.y, h0.y), 0.f));
                float v2 = b2f(av.y & 0xffff), v3 = b2f(av.y >> 16);
                ov.y = pack2(fmaxf(fmaf(v2, s0.z, h0.z), 0.f),
                             fmaxf(fmaf(v3, s0.w, h0.w), 0.f));
                float v4 = b2f(av.z & 0xffff), v5 = b2f(av.z >> 16);
                ov.z = pack2(fmaxf(fmaf(v4, s1.x, h1.x), 0.f),
                             fmaxf(fmaf(v5, s1.y, h1.y), 0.f));
                float v6 = b2f(av.w & 0xffff), v7 = b2f(av.w >> 16);
                ov.w = pack2(fmaxf(fmaf(v6, s1.z, h1.z), 0.f),
                             fmaxf(fmaf(v7, s1.w, h1.w), 0.f));
            }
            *(uint4*)(asw + ssw * 8) = ov;
            uint4 bv = *(const uint4*)(bptr + c0);
            *(uint4*)(bsw + ssw * 8) = bv;
        }
        __syncthreads();
#pragma unroll
        for (int ks = 0; ks < 2; ++ks) {
            bf16x8 af[4], bfr[4];
#pragma unroll
            for (int fr = 0; fr < 4; ++fr) {
                const int row = wm * 64 + fr * 16 + (lane & 15);
                const int slot = (ks * 4 + (lane >> 4)) ^ (row & 7);
                af[fr] = *(const bf16x8*)&As[row * 64 + slot * 8];
            }
#pragma unroll
            for (int fc = 0; fc < 4; ++fc) {
                const int row = wn * 64 + fc * 16 + (lane & 15);
                const int slot = (ks * 4 + (lane >> 4)) ^ (row & 7);
                bfr[fc] = *(const bf16x8*)&Bs[row * 64 + slot * 8];
            }
#pragma unroll
            for (int fr = 0; fr < 4; ++fr)
#pragma unroll
                for (int fc = 0; fc < 4; ++fc)
                    acc[fr][fc] = __builtin_amdgcn_mfma_f32_16x16x32_bf16(
                        af[fr], bfr[fc], acc[fr][fc], 0, 0, 0);
        }
        __syncthreads();
    }

#pragma unroll
    for (int fc = 0; fc < 4; ++fc) {
        const int cl = wn * 64 + fc * 16 + (lane & 15);
        const float bv = bias[cl];
        float s = 0.0f, q = 0.0f;
#pragma unroll
        for (int fr = 0; fr < 4; ++fr) {
#pragma unroll
            for (int j = 0; j < 4; ++j) {
                const int m = r0 + wm * 64 + fr * 16 + (lane >> 4) * 4 + j;
                const float v = acc[fr][fc][j] + bv;
                y1[(size_t)m * O1 + cl] = v;
                s += v;
                q = fmaf(v, v, q);
            }
        }
        s += __shfl_xor(s, 16); s += __shfl_xor(s, 32);
        q += __shfl_xor(q, 16); q += __shfl_xor(q, 32);
        if ((lane >> 4) == 0) { cps[wm][cl][0] = s; cps[wm][cl][1] = q; }
    }
    __syncthreads();
    if (t < 128) {
        ps[(size_t)blockIdx.x * 128 + t] = cps[0][t][0] + cps[1][t][0];
        pq[(size_t)blockIdx.x * 128 + t] = cps[0][t][1] + cps[1][t][1];
    }
}

__global__ __launch_bounds__(512) void k_fin1(const float* __restrict__ ps,
                                              const float* __restrict__ pq,
                                              const float* __restrict__ gamma,
                                              const float* __restrict__ beta,
                                              float* __restrict__ sc,
                                              float* __restrict__ sh) {
    __shared__ float red[4][128][2];
    const int tid = threadIdx.x;
    const int c = tid & 127, qr = tid >> 7;
    float s = 0.0f, q = 0.0f;
    for (int bx = qr * 128; bx < qr * 128 + 128; ++bx) {
        s += ps[(size_t)bx * 128 + c];
        q += pq[(size_t)bx * 128 + c];
    }
    red[qr][c][0] = s; red[qr][c][1] = q;
    __syncthreads();
    if (tid < 128) {
        const float ss = ((red[0][tid][0] + red[1][tid][0]) +
                          (red[2][tid][0] + red[3][tid][0]));
        const float qq = ((red[0][tid][1] + red[1][tid][1]) +
                          (red[2][tid][1] + red[3][tid][1]));
        const float mean = ss * (1.0f / NROWS);
        const float var = qq * (1.0f / NROWS) - mean * mean;
        const float rs = rsqrtf(var + 1e-5f);
        const float scale = gamma[tid] * rs;
        sc[tid] = scale;
        sh[tid] = beta[tid] - mean * scale;
    }
}

// In-place BN + ReLU on d_out (one float4 per thread).
__global__ __launch_bounds__(256) void k_bnrelu(float* __restrict__ y,
                                                const float* __restrict__ sc,
                                                const float* __restrict__ sh) {
    const int e4 = blockIdx.x * 256 + threadIdx.x;
    const int c = (e4 & 31) << 2;
    float4 v = *(float4*)&y[(size_t)e4 * 4];
    const float4 s4 = *(const float4*)&sc[c];
    const float4 h4 = *(const float4*)&sh[c];
    v.x = fmaxf(fmaf(v.x, s4.x, h4.x), 0.0f);
    v.y = fmaxf(fmaf(v.y, s4.y, h4.y), 0.0f);
    v.z = fmaxf(fmaf(v.z, s4.z, h4.z), 0.0f);
    v.w = fmaxf(fmaf(v.w, s4.w, h4.w), 0.0f);
    *(float4*)&y[(size_t)e4 * 4] = v;
}

// ---------------------------------------------------------------------------
extern "C" void kernel_launch(void* const* d_in, const int* in_sizes, int n_in,
                              void* d_out, int out_size, void* d_ws, size_t ws_size,
                              hipStream_t stream) {
    const float* xyz1    = (const float*)d_in[0];
    const float* xyz2    = (const float*)d_in[1];
    const float* points1 = (const float*)d_in[2];
    const float* points2 = (const float*)d_in[3];
    const float* W0      = (const float*)d_in[4];
    const float* b0      = (const float*)d_in[5];
    const float* gamma0  = (const float*)d_in[6];
    const float* beta0   = (const float*)d_in[7];
    const float* W1      = (const float*)d_in[8];
    const float* b1      = (const float*)d_in[9];
    const float* gamma1  = (const float*)d_in[10];
    const float* beta1   = (const float*)d_in[11];
    float* out = (float*)d_out;

    char* ws = (char*)d_ws;
    unsigned short* x   = (unsigned short*)(ws + 0);            // 50,331,648 B
    unsigned short* y0  = (unsigned short*)(ws + 50331648ull);  // 33,554,432 B
    int*            idxb= (int*)           (ws + 83886080ull);  //    786,432 B
    float*          wb  = (float*)         (ws + 84672512ull);  //    786,432 B
    unsigned short* Wb0 = (unsigned short*)(ws + 85458944ull);  //    196,608 B
    unsigned short* Wb1 = (unsigned short*)(ws + 85655552ull);  //     65,536 B
    float*          ps0 = (float*)         (ws + 85721088ull);  //    524,288 B
    float*          pq0 = (float*)         (ws + 86245376ull);  //    524,288 B
    float*          ps1 = (float*)         (ws + 86769664ull);  //    262,144 B
    float*          pq1 = (float*)         (ws + 87031808ull);  //    262,144 B
    float*          sc0 = (float*)         (ws + 87293952ull);
    float*          sh0 = (float*)         (ws + 87295232ull);
    float*          sc1 = (float*)         (ws + 87296512ull);
    float*          sh1 = (float*)         (ws + 87297792ull);

    hipLaunchKernelGGL(k_cvt, dim3(512), dim3(256), 0, stream, W0, W1, Wb0, Wb1);
    hipLaunchKernelGGL(k_knn, dim3(1024), dim3(256), 0, stream, xyz1, xyz2, idxb, wb);
    hipLaunchKernelGGL(k_interp, dim3(NROWS / 16), dim3(256), 0, stream,
                       points1, points2, idxb, wb, x);
    hipLaunchKernelGGL(k_gemm0, dim3(NROWS / 128), dim3(512), 0, stream,
                       x, Wb0, b0, y0, ps0, pq0);
    hipLaunchKernelGGL(k_fin0, dim3(1), dim3(1024), 0, stream,
                       ps0, pq0, gamma0, beta0, sc0, sh0);
    hipLaunchKernelGGL(k_gemm1, dim3(NROWS / 128), dim3(256), 0, stream,
                       y0, Wb1, b1, sc0, sh0, out, ps1, pq1);
    hipLaunchKernelGGL(k_fin1, dim3(1), dim3(512), 0, stream,
                       ps1, pq1, gamma1, beta1, sc1, sh1);
    hipLaunchKernelGGL(k_bnrelu, dim3(NROWS * O1 / 4 / 256), dim3(256), 0, stream,
                       out, sc1, sh1);
}